// Round 1
// baseline (690.459 us; speedup 1.0000x reference)
//
#include <hip/hip_runtime.h>
#include <hip/hip_bf16.h>

#define NN 50000
#define EE 800000
#define CCH 128
#define KTOP 25000
#define EPSF 1e-5

// ---------------------------------------------------------------------------
// GEMM: C[M,128] = A[M,128] @ W[128,128] (+ bias). f32, W fully in LDS.
// block 256 threads, tile 128 rows x 128 cols, 8x8 micro-tile per thread.
// ---------------------------------------------------------------------------
__global__ __launch_bounds__(256, 2) void gemm128(const float* __restrict__ A,
                                                  const float* __restrict__ W,
                                                  const float* __restrict__ bias,
                                                  float* __restrict__ Cout, int M) {
    __shared__ float Bs[128][128];   // 64 KiB: W, [k][n]
    __shared__ float As[32][128];    // 16 KiB: A-chunk transposed, [k][row]
    int t = threadIdx.x;
    int bm = blockIdx.x * 128;

    const float4* W4 = (const float4*)W;
    float4* Bs4 = (float4*)Bs;
#pragma unroll
    for (int i = 0; i < 16; i++) Bs4[t + i * 256] = W4[t + i * 256];

    float acc[8][8];
#pragma unroll
    for (int i = 0; i < 8; i++)
#pragma unroll
        for (int j = 0; j < 8; j++) acc[i][j] = 0.f;

    int ty = t >> 4;   // 0..15 row group
    int tx = t & 15;   // 0..15 col group

    for (int kc = 0; kc < 4; kc++) {
        __syncthreads();
        // stage A chunk: 128 rows x 32 k, transposed into As[k][row]
#pragma unroll
        for (int i = 0; i < 4; i++) {
            int f4 = t + i * 256;          // 0..1023
            int r = f4 >> 3, k4 = f4 & 7;  // r: 0..127, k4: 0..7
            int row = bm + r;
            float4 v = make_float4(0.f, 0.f, 0.f, 0.f);
            if (row < M) v = *(const float4*)&A[row * 128 + kc * 32 + k4 * 4];
            As[k4 * 4 + 0][r] = v.x;
            As[k4 * 4 + 1][r] = v.y;
            As[k4 * 4 + 2][r] = v.z;
            As[k4 * 4 + 3][r] = v.w;
        }
        __syncthreads();
#pragma unroll
        for (int kk = 0; kk < 32; kk++) {
            float4 a0 = *(float4*)&As[kk][ty * 8];
            float4 a1 = *(float4*)&As[kk][ty * 8 + 4];
            float4 b0 = *(float4*)&Bs[kc * 32 + kk][tx * 8];
            float4 b1 = *(float4*)&Bs[kc * 32 + kk][tx * 8 + 4];
            float av[8] = {a0.x, a0.y, a0.z, a0.w, a1.x, a1.y, a1.z, a1.w};
            float bv[8] = {b0.x, b0.y, b0.z, b0.w, b1.x, b1.y, b1.z, b1.w};
#pragma unroll
            for (int i = 0; i < 8; i++)
#pragma unroll
                for (int j = 0; j < 8; j++) acc[i][j] += av[i] * bv[j];
        }
    }
#pragma unroll
    for (int i = 0; i < 8; i++) {
        int row = bm + ty * 8 + i;
        if (row < M) {
#pragma unroll
            for (int j = 0; j < 8; j++) {
                float b = bias ? bias[tx * 8 + j] : 0.f;
                Cout[row * 128 + tx * 8 + j] = acc[i][j] + b;
            }
        }
    }
}

// ---------------------------------------------------------------------------
// BatchNorm stats: per-channel sum/sumsq (f64 partials), 2-stage deterministic
// ---------------------------------------------------------------------------
#define BN_ROWS 256
#define BN_NB ((NN + BN_ROWS - 1) / BN_ROWS)   // 196

__global__ __launch_bounds__(128) void bn_stats_partial(const float* __restrict__ Y,
                                                        double* __restrict__ part, int M) {
    int c = threadIdx.x;
    int b = blockIdx.x;
    int r0 = b * BN_ROWS;
    int r1 = min(M, r0 + BN_ROWS);
    double s = 0.0, s2 = 0.0;
    for (int r = r0; r < r1; r++) {
        float v = Y[r * 128 + c];
        s += (double)v;
        s2 += (double)v * (double)v;
    }
    part[(b * 128 + c) * 2 + 0] = s;
    part[(b * 128 + c) * 2 + 1] = s2;
}

__global__ __launch_bounds__(128) void bn_finalize(const double* __restrict__ part, int nb,
                                                   const float* __restrict__ g,
                                                   const float* __restrict__ beta,
                                                   float* __restrict__ scale,
                                                   float* __restrict__ shift, int M) {
    int c = threadIdx.x;
    double s = 0.0, s2 = 0.0;
    for (int b = 0; b < nb; b++) {
        s += part[(b * 128 + c) * 2 + 0];
        s2 += part[(b * 128 + c) * 2 + 1];
    }
    double mu = s / (double)M;
    double var = s2 / (double)M - mu * mu;
    double inv = 1.0 / sqrt(var + (double)EPSF);
    float sc = (float)((double)g[c] * inv);
    scale[c] = sc;
    shift[c] = (float)((double)beta[c] - mu * (double)g[c] * inv);
}

__global__ __launch_bounds__(256) void bn_apply_relu(const float* __restrict__ Y,
                                                     const float* __restrict__ scale,
                                                     const float* __restrict__ shift,
                                                     float* __restrict__ H, int nf4) {
    int i = blockIdx.x * 256 + threadIdx.x;
    if (i >= nf4) return;
    float4 v = ((const float4*)Y)[i];
    int c = (i * 4) & 127;
    float r0 = v.x * scale[c + 0] + shift[c + 0];
    float r1 = v.y * scale[c + 1] + shift[c + 1];
    float r2 = v.z * scale[c + 2] + shift[c + 2];
    float r3 = v.w * scale[c + 3] + shift[c + 3];
    float4 o;
    o.x = r0 > 0.f ? r0 : 0.f;
    o.y = r1 > 0.f ? r1 : 0.f;
    o.z = r2 > 0.f ? r2 : 0.f;
    o.w = r3 > 0.f ? r3 : 0.f;
    ((float4*)H)[i] = o;
}

// ---------------------------------------------------------------------------
// Graph: degree count, dinv, CSR build
// ---------------------------------------------------------------------------
__global__ __launch_bounds__(256) void count_deg(const int* __restrict__ col,
                                                 int* __restrict__ cnt, int E) {
    int e = blockIdx.x * 256 + threadIdx.x;
    if (e < E) atomicAdd(&cnt[col[e]], 1);
}

__global__ __launch_bounds__(256) void dinv_kernel(const int* __restrict__ cnt,
                                                   float* __restrict__ dinv, int M) {
    int i = blockIdx.x * 256 + threadIdx.x;
    if (i < M) {
        double deg = (double)(cnt[i] + 1);   // +1 self loop
        dinv[i] = (float)(1.0 / sqrt(deg));
    }
}

__global__ __launch_bounds__(256) void fill_csr(const int* __restrict__ row,
                                                const int* __restrict__ col,
                                                const int* __restrict__ off,
                                                int* __restrict__ cur,
                                                int* __restrict__ csr, int E) {
    int e = blockIdx.x * 256 + threadIdx.x;
    if (e < E) {
        int c = col[e];
        int p = atomicAdd(&cur[c], 1);
        csr[off[c] + p] = row[e];
    }
}

// ---------------------------------------------------------------------------
// Scan (3-phase exclusive scan; also writes out[n] = total)
// ---------------------------------------------------------------------------
__device__ __forceinline__ int waveInclScan(int v, int lane) {
#pragma unroll
    for (int o = 1; o < 64; o <<= 1) {
        int u = __shfl_up(v, o, 64);
        if (lane >= o) v += u;
    }
    return v;
}

__global__ __launch_bounds__(1024) void scan_phase1(const int* __restrict__ in,
                                                    int* __restrict__ out,
                                                    int* __restrict__ bsum, int n) {
    int t = threadIdx.x;
    int g = blockIdx.x * 1024 + t;
    int lane = t & 63, wid = t >> 6;
    int v = (g < n) ? in[g] : 0;
    int incl = waveInclScan(v, lane);
    __shared__ int ws[16];
    if (lane == 63) ws[wid] = incl;
    __syncthreads();
    if (t < 16) {
        int x = ws[t];
#pragma unroll
        for (int o = 1; o < 16; o <<= 1) {
            int u = __shfl_up(x, o, 64);
            if (t >= o) x += u;
        }
        ws[t] = x;
    }
    __syncthreads();
    int pre = (wid > 0) ? ws[wid - 1] : 0;
    if (g < n) out[g] = pre + incl - v;
    if (t == 1023) bsum[blockIdx.x] = ws[15];
}

__global__ __launch_bounds__(1024) void scan_phase2(int* __restrict__ bsum, int B,
                                                    int* __restrict__ out, int n) {
    int t = threadIdx.x;
    int lane = t & 63, wid = t >> 6;
    int v = (t < B) ? bsum[t] : 0;
    int incl = waveInclScan(v, lane);
    __shared__ int ws[16];
    if (lane == 63) ws[wid] = incl;
    __syncthreads();
    if (t < 16) {
        int x = ws[t];
#pragma unroll
        for (int o = 1; o < 16; o <<= 1) {
            int u = __shfl_up(x, o, 64);
            if (t >= o) x += u;
        }
        ws[t] = x;
    }
    __syncthreads();
    int pre = (wid > 0) ? ws[wid - 1] : 0;
    int glob_incl = pre + incl;
    if (t < B) bsum[t] = glob_incl - v;   // exclusive
    if (t == B - 1) out[n] = glob_incl;   // grand total
}

__global__ __launch_bounds__(1024) void scan_phase3(int* __restrict__ out,
                                                    const int* __restrict__ bsum, int n) {
    int g = blockIdx.x * 1024 + threadIdx.x;
    if (g < n) out[g] += bsum[blockIdx.x];
}

// ---------------------------------------------------------------------------
// GCN aggregation: one block (128 thr) per node, f64 accumulate
// agg[i,c] = dinv[i]*( sum_src dinv[src]*HW[src,c] + dinv[i]*HW[i,c] ) + gcn_b[c]
// ---------------------------------------------------------------------------
__global__ __launch_bounds__(128) void gcn_agg(const float* __restrict__ HW,
                                               const int* __restrict__ off,
                                               const int* __restrict__ csr,
                                               const float* __restrict__ dinv,
                                               const float* __restrict__ gcn_b,
                                               float* __restrict__ OUT, int M) {
    int i = blockIdx.x;
    int c = threadIdx.x;
    int o0 = off[i], o1 = off[i + 1];
    double di = (double)dinv[i];
    double acc = di * (double)HW[i * 128 + c];   // self loop (one dinv factor applied at end)
    for (int e = o0; e < o1; e++) {
        int s = csr[e];
        acc += (double)dinv[s] * (double)HW[s * 128 + c];
    }
    OUT[i * 128 + c] = (float)(acc * di) + gcn_b[c];
}

// ---------------------------------------------------------------------------
// Score + orderable key + bucket histogram. One wave per row.
// ---------------------------------------------------------------------------
__global__ __launch_bounds__(256) void score_key(const float* __restrict__ H2,
                                                 const float* __restrict__ w,
                                                 float* __restrict__ score,
                                                 unsigned* __restrict__ key,
                                                 int* __restrict__ bcnt, int M) {
    int lane = threadIdx.x & 63;
    int wid = threadIdx.x >> 6;
    int gw = blockIdx.x * 4 + wid;
    int nw = gridDim.x * 4;

    float nv = w[lane] * w[lane] + w[lane + 64] * w[lane + 64];
#pragma unroll
    for (int o = 32; o >= 1; o >>= 1) nv += __shfl_xor(nv, o, 64);
    float nrm = sqrtf(nv);

    for (int r = gw; r < M; r += nw) {
        float v = H2[r * 128 + lane] * w[lane] + H2[r * 128 + lane + 64] * w[lane + 64];
#pragma unroll
        for (int o = 32; o >= 1; o >>= 1) v += __shfl_xor(v, o, 64);
        if (lane == 0) {
            float s = tanhf(v / nrm);
            score[r] = s;
            unsigned u = __float_as_uint(s);
            unsigned k = (u & 0x80000000u) ? ~u : (u | 0x80000000u);
            key[r] = k;
            atomicAdd(&bcnt[k >> 16], 1);
        }
    }
}

__global__ __launch_bounds__(256) void bucket_fill(const unsigned* __restrict__ key,
                                                   const int* __restrict__ boff,
                                                   int* __restrict__ bcur,
                                                   int* __restrict__ bmem, int M) {
    int i = blockIdx.x * 256 + threadIdx.x;
    if (i < M) {
        int b = key[i] >> 16;
        int p = atomicAdd(&bcur[b], 1);
        bmem[boff[b] + p] = i;
    }
}

__global__ __launch_bounds__(256) void rank_kernel(const unsigned* __restrict__ key,
                                                   const int* __restrict__ boff,
                                                   const int* __restrict__ bmem,
                                                   int* __restrict__ rank,
                                                   int* __restrict__ nidx, int M) {
    int i = blockIdx.x * 256 + threadIdx.x;
    if (i >= M) return;
    unsigned ki = key[i];
    int b = ki >> 16;
    int r = M - boff[b + 1];   // all keys in strictly-greater buckets
    int p0 = boff[b], p1 = boff[b + 1];
    for (int p = p0; p < p1; p++) {
        int j = bmem[p];
        unsigned kj = key[j];
        if (kj > ki || (kj == ki && j < i)) r++;
    }
    rank[i] = r;
    nidx[i] = (r < KTOP) ? r : -1;
}

// ---------------------------------------------------------------------------
// Output writers (d_out is float32: [x_pool K*128 | ei_new 2E | batch_new K])
// ---------------------------------------------------------------------------
__global__ __launch_bounds__(128) void write_pool(const float* __restrict__ H2,
                                                  const float* __restrict__ score,
                                                  const int* __restrict__ rank,
                                                  float* __restrict__ out0,
                                                  float* __restrict__ out2, int M) {
    int i = blockIdx.x;
    int c = threadIdx.x;
    int r = rank[i];
    if (r < KTOP) {
        float s = score[i];
        out0[r * 128 + c] = H2[i * 128 + c] * s;
        if (c == 0) out2[r] = 0.0f;   // batch_new (batch is all zeros)
    }
}

__global__ __launch_bounds__(256) void write_edges(const int* __restrict__ row,
                                                   const int* __restrict__ col,
                                                   const int* __restrict__ nidx,
                                                   float* __restrict__ out1, int E) {
    int e = blockIdx.x * 256 + threadIdx.x;
    if (e < E) {
        int a = nidx[row[e]];
        int b = nidx[col[e]];
        bool keep = (a >= 0) && (b >= 0);
        out1[e] = keep ? (float)a : -1.0f;
        out1[E + e] = keep ? (float)b : -1.0f;
    }
}

// ---------------------------------------------------------------------------
extern "C" void kernel_launch(void* const* d_in, const int* in_sizes, int n_in,
                              void* d_out, int out_size, void* d_ws, size_t ws_size,
                              hipStream_t stream) {
    const float* x = (const float*)d_in[0];
    const int* ei = (const int*)d_in[1];
    const float* lin_w = (const float*)d_in[3];
    const float* lin_b = (const float*)d_in[4];
    const float* bn1_g = (const float*)d_in[5];
    const float* bn1_b = (const float*)d_in[6];
    const float* gcn_w = (const float*)d_in[7];
    const float* gcn_b = (const float*)d_in[8];
    const float* bn2_g = (const float*)d_in[9];
    const float* bn2_b = (const float*)d_in[10];
    const float* pool_w = (const float*)d_in[11];

    const int* e_row = ei;        // edge_index[0]
    const int* e_col = ei + EE;   // edge_index[1]

    char* ws = (char*)d_ws;
    size_t off_b = 0;
    auto alloc = [&](size_t bytes) -> void* {
        void* p = ws + off_b;
        off_b = (off_b + bytes + 255) & ~(size_t)255;
        return p;
    };
    float* y = (float*)alloc((size_t)NN * 128 * 4);     // gemm1 out, later gcn out
    float* h = (float*)alloc((size_t)NN * 128 * 4);     // h, later h2
    float* hw = (float*)alloc((size_t)NN * 128 * 4);    // h @ gcn_w
    int* cnt = (int*)alloc(NN * 4);
    int* cur = (int*)alloc(NN * 4);
    int* offs = (int*)alloc((NN + 1) * 4);
    float* dinv = (float*)alloc(NN * 4);
    int* csr = (int*)alloc((size_t)EE * 4);
    float* score = (float*)alloc(NN * 4);
    unsigned* key = (unsigned*)alloc(NN * 4);
    int* rank = (int*)alloc(NN * 4);
    int* nidx = (int*)alloc(NN * 4);
    int* bcnt = (int*)alloc(65536 * 4);
    int* boff = (int*)alloc((65536 + 1) * 4);
    int* bcur = (int*)alloc(65536 * 4);
    int* bmem = (int*)alloc(NN * 4);
    double* part = (double*)alloc((size_t)BN_NB * 128 * 2 * 8);
    float* scale1 = (float*)alloc(128 * 4);
    float* shift1 = (float*)alloc(128 * 4);
    float* scale2 = (float*)alloc(128 * 4);
    float* shift2 = (float*)alloc(128 * 4);
    int* bsum = (int*)alloc(128 * 4);

    float* out0 = (float*)d_out;                       // x_pool [K,128]
    float* out1 = out0 + (size_t)KTOP * 128;           // ei_new [2,E]
    float* out2 = out1 + (size_t)2 * EE;               // batch_new [K]

    int gemm_grid = (NN + 127) / 128;                  // 391

    // ---- MLP: Linear + BN + ReLU ----
    gemm128<<<gemm_grid, 256, 0, stream>>>(x, lin_w, lin_b, y, NN);
    bn_stats_partial<<<BN_NB, 128, 0, stream>>>(y, part, NN);
    bn_finalize<<<1, 128, 0, stream>>>(part, BN_NB, bn1_g, bn1_b, scale1, shift1, NN);
    bn_apply_relu<<<(NN * 128 / 4 + 255) / 256, 256, 0, stream>>>(y, scale1, shift1, h, NN * 128 / 4);

    // ---- GCN ----
    gemm128<<<gemm_grid, 256, 0, stream>>>(h, gcn_w, nullptr, hw, NN);
    hipMemsetAsync(cnt, 0, NN * 4, stream);
    count_deg<<<(EE + 255) / 256, 256, 0, stream>>>(e_col, cnt, EE);
    dinv_kernel<<<(NN + 255) / 256, 256, 0, stream>>>(cnt, dinv, NN);
    {
        int B = (NN + 1023) / 1024;
        scan_phase1<<<B, 1024, 0, stream>>>(cnt, offs, bsum, NN);
        scan_phase2<<<1, 1024, 0, stream>>>(bsum, B, offs, NN);
        scan_phase3<<<B, 1024, 0, stream>>>(offs, bsum, NN);
    }
    hipMemsetAsync(cur, 0, NN * 4, stream);
    fill_csr<<<(EE + 255) / 256, 256, 0, stream>>>(e_row, e_col, offs, cur, csr, EE);
    gcn_agg<<<NN, 128, 0, stream>>>(hw, offs, csr, dinv, gcn_b, y, NN);

    // ---- BN2 + ReLU -> h2 (in h) ----
    bn_stats_partial<<<BN_NB, 128, 0, stream>>>(y, part, NN);
    bn_finalize<<<1, 128, 0, stream>>>(part, BN_NB, bn2_g, bn2_b, scale2, shift2, NN);
    bn_apply_relu<<<(NN * 128 / 4 + 255) / 256, 256, 0, stream>>>(y, scale2, shift2, h, NN * 128 / 4);

    // ---- TopK pooling ----
    hipMemsetAsync(bcnt, 0, 65536 * 4, stream);
    score_key<<<512, 256, 0, stream>>>(h, pool_w, score, key, bcnt, NN);
    {
        int B = 65536 / 1024;
        scan_phase1<<<B, 1024, 0, stream>>>(bcnt, boff, bsum, 65536);
        scan_phase2<<<1, 1024, 0, stream>>>(bsum, B, boff, 65536);
        scan_phase3<<<B, 1024, 0, stream>>>(boff, bsum, 65536);
    }
    hipMemsetAsync(bcur, 0, 65536 * 4, stream);
    bucket_fill<<<(NN + 255) / 256, 256, 0, stream>>>(key, boff, bcur, bmem, NN);
    rank_kernel<<<(NN + 255) / 256, 256, 0, stream>>>(key, boff, bmem, rank, nidx, NN);

    // ---- outputs ----
    write_pool<<<NN, 128, 0, stream>>>(h, score, rank, out0, out2, NN);
    write_edges<<<(EE + 255) / 256, 256, 0, stream>>>(e_row, e_col, nidx, out1, EE);
}

// Round 2
// 672.013 us; speedup vs baseline: 1.0274x; 1.0274x over previous
//
#include <hip/hip_runtime.h>
#include <hip/hip_bf16.h>

#define NN 50000
#define EE 800000
#define KTOP 25000
#define EPSF 1e-5

// ---------------------------------------------------------------------------
// GEMM1: Y[M,128] = A[M,128] @ W[128,128] + bias, fused per-block BN partials.
// block 256 threads, tile 128x128, 8x8 micro-tile. part[bid][c] = (sum,sumsq)
// ---------------------------------------------------------------------------
__global__ __launch_bounds__(256, 2) void gemm_bn_stats(const float* __restrict__ A,
                                                        const float* __restrict__ W,
                                                        const float* __restrict__ bias,
                                                        float* __restrict__ Y,
                                                        double* __restrict__ part, int M) {
    __shared__ float Bs[128][128];   // 64 KiB: W, [k][n]
    __shared__ float As[32][128];    // 16 KiB: A-chunk transposed, [k][row]
    int t = threadIdx.x;
    int bm = blockIdx.x * 128;

    const float4* W4 = (const float4*)W;
    float4* Bs4 = (float4*)Bs;
#pragma unroll
    for (int i = 0; i < 16; i++) Bs4[t + i * 256] = W4[t + i * 256];

    float acc[8][8];
#pragma unroll
    for (int i = 0; i < 8; i++)
#pragma unroll
        for (int j = 0; j < 8; j++) acc[i][j] = 0.f;

    int ty = t >> 4;   // 0..15 row group
    int tx = t & 15;   // 0..15 col group

    for (int kc = 0; kc < 4; kc++) {
        __syncthreads();
#pragma unroll
        for (int i = 0; i < 4; i++) {
            int f4 = t + i * 256;
            int r = f4 >> 3, k4 = f4 & 7;
            int row = bm + r;
            float4 v = make_float4(0.f, 0.f, 0.f, 0.f);
            if (row < M) v = *(const float4*)&A[(size_t)row * 128 + kc * 32 + k4 * 4];
            As[k4 * 4 + 0][r] = v.x;
            As[k4 * 4 + 1][r] = v.y;
            As[k4 * 4 + 2][r] = v.z;
            As[k4 * 4 + 3][r] = v.w;
        }
        __syncthreads();
#pragma unroll
        for (int kk = 0; kk < 32; kk++) {
            float4 a0 = *(float4*)&As[kk][ty * 8];
            float4 a1 = *(float4*)&As[kk][ty * 8 + 4];
            float4 b0 = *(float4*)&Bs[kc * 32 + kk][tx * 8];
            float4 b1 = *(float4*)&Bs[kc * 32 + kk][tx * 8 + 4];
            float av[8] = {a0.x, a0.y, a0.z, a0.w, a1.x, a1.y, a1.z, a1.w};
            float bv[8] = {b0.x, b0.y, b0.z, b0.w, b1.x, b1.y, b1.z, b1.w};
#pragma unroll
            for (int i = 0; i < 8; i++)
#pragma unroll
                for (int j = 0; j < 8; j++) acc[i][j] += av[i] * bv[j];
        }
    }

    // epilogue: write Y and per-thread channel partials over its 8 rows
    float s[8], s2[8];
#pragma unroll
    for (int j = 0; j < 8; j++) { s[j] = 0.f; s2[j] = 0.f; }
#pragma unroll
    for (int i = 0; i < 8; i++) {
        int row = bm + ty * 8 + i;
        if (row < M) {
#pragma unroll
            for (int j = 0; j < 8; j++) {
                float yv = acc[i][j] + bias[tx * 8 + j];
                Y[(size_t)row * 128 + tx * 8 + j] = yv;
                s[j] += yv;
                s2[j] += yv * yv;
            }
        }
    }
    __syncthreads();                       // As no longer needed
    float2* Sred = (float2*)As;            // [16][128] = 16 KiB exactly
#pragma unroll
    for (int j = 0; j < 8; j++) Sred[ty * 128 + tx * 8 + j] = make_float2(s[j], s2[j]);
    __syncthreads();
    if (t < 128) {
        double S = 0.0, S2 = 0.0;
#pragma unroll
        for (int r = 0; r < 16; r++) {
            float2 v = Sred[r * 128 + t];
            S += (double)v.x;
            S2 += (double)v.y;
        }
        part[((size_t)blockIdx.x * 128 + t) * 2 + 0] = S;
        part[((size_t)blockIdx.x * 128 + t) * 2 + 1] = S2;
    }
}

// ---------------------------------------------------------------------------
// GEMM2: HWs[M,128] = dinv[row] * ( relu(bn1(Yin)) @ W ).  BN1 applied on the
// fly during A-staging; dinv scaling in epilogue.
// ---------------------------------------------------------------------------
__global__ __launch_bounds__(256, 2) void gemm_bn_apply(const float* __restrict__ Yin,
                                                        const float* __restrict__ W,
                                                        const float* __restrict__ sc,
                                                        const float* __restrict__ sh,
                                                        const float* __restrict__ dinv,
                                                        float* __restrict__ HWs, int M) {
    __shared__ float Bs[128][128];
    __shared__ float As[32][128];
    int t = threadIdx.x;
    int bm = blockIdx.x * 128;

    const float4* W4 = (const float4*)W;
    float4* Bs4 = (float4*)Bs;
#pragma unroll
    for (int i = 0; i < 16; i++) Bs4[t + i * 256] = W4[t + i * 256];

    float acc[8][8];
#pragma unroll
    for (int i = 0; i < 8; i++)
#pragma unroll
        for (int j = 0; j < 8; j++) acc[i][j] = 0.f;

    int ty = t >> 4;
    int tx = t & 15;

    for (int kc = 0; kc < 4; kc++) {
        __syncthreads();
#pragma unroll
        for (int i = 0; i < 4; i++) {
            int f4 = t + i * 256;
            int r = f4 >> 3, k4 = f4 & 7;
            int row = bm + r;
            int col = kc * 32 + k4 * 4;
            float4 v = make_float4(0.f, 0.f, 0.f, 0.f);
            if (row < M) {
                float4 y = *(const float4*)&Yin[(size_t)row * 128 + col];
                float4 scv = *(const float4*)&sc[col];
                float4 shv = *(const float4*)&sh[col];
                v.x = fmaxf(y.x * scv.x + shv.x, 0.f);
                v.y = fmaxf(y.y * scv.y + shv.y, 0.f);
                v.z = fmaxf(y.z * scv.z + shv.z, 0.f);
                v.w = fmaxf(y.w * scv.w + shv.w, 0.f);
            }
            As[k4 * 4 + 0][r] = v.x;
            As[k4 * 4 + 1][r] = v.y;
            As[k4 * 4 + 2][r] = v.z;
            As[k4 * 4 + 3][r] = v.w;
        }
        __syncthreads();
#pragma unroll
        for (int kk = 0; kk < 32; kk++) {
            float4 a0 = *(float4*)&As[kk][ty * 8];
            float4 a1 = *(float4*)&As[kk][ty * 8 + 4];
            float4 b0 = *(float4*)&Bs[kc * 32 + kk][tx * 8];
            float4 b1 = *(float4*)&Bs[kc * 32 + kk][tx * 8 + 4];
            float av[8] = {a0.x, a0.y, a0.z, a0.w, a1.x, a1.y, a1.z, a1.w};
            float bv[8] = {b0.x, b0.y, b0.z, b0.w, b1.x, b1.y, b1.z, b1.w};
#pragma unroll
            for (int i = 0; i < 8; i++)
#pragma unroll
                for (int j = 0; j < 8; j++) acc[i][j] += av[i] * bv[j];
        }
    }
#pragma unroll
    for (int i = 0; i < 8; i++) {
        int row = bm + ty * 8 + i;
        if (row < M) {
            float di = dinv[row];
#pragma unroll
            for (int j = 0; j < 8; j++)
                HWs[(size_t)row * 128 + tx * 8 + j] = acc[i][j] * di;
        }
    }
}

// ---------------------------------------------------------------------------
// BN stats (for gcn output): 64 rows/block, unroll-4, f64 partials
// ---------------------------------------------------------------------------
#define BN2_ROWS 64
#define BN2_NB ((NN + BN2_ROWS - 1) / BN2_ROWS)   // 782

__global__ __launch_bounds__(128) void bn_stats(const float* __restrict__ Y,
                                                double* __restrict__ part, int M) {
    int c = threadIdx.x;
    int b = blockIdx.x;
    int r0 = b * BN2_ROWS;
    int r1 = min(M, r0 + BN2_ROWS);
    double s = 0.0, s2 = 0.0;
    int r = r0;
    for (; r + 4 <= r1; r += 4) {
        float v0 = Y[(size_t)r * 128 + c];
        float v1 = Y[(size_t)(r + 1) * 128 + c];
        float v2 = Y[(size_t)(r + 2) * 128 + c];
        float v3 = Y[(size_t)(r + 3) * 128 + c];
        s += (double)v0 + (double)v1 + (double)v2 + (double)v3;
        s2 += (double)v0 * v0 + (double)v1 * v1 + (double)v2 * v2 + (double)v3 * v3;
    }
    for (; r < r1; r++) {
        float v = Y[(size_t)r * 128 + c];
        s += (double)v;
        s2 += (double)v * v;
    }
    part[((size_t)b * 128 + c) * 2 + 0] = s;
    part[((size_t)b * 128 + c) * 2 + 1] = s2;
}

__global__ __launch_bounds__(128) void bn_finalize(const double* __restrict__ part, int nb,
                                                   const float* __restrict__ g,
                                                   const float* __restrict__ beta,
                                                   float* __restrict__ scale,
                                                   float* __restrict__ shift, int M) {
    int c = threadIdx.x;
    double s = 0.0, s2 = 0.0;
    for (int b = 0; b < nb; b++) {
        s += part[((size_t)b * 128 + c) * 2 + 0];
        s2 += part[((size_t)b * 128 + c) * 2 + 1];
    }
    double mu = s / (double)M;
    double var = s2 / (double)M - mu * mu;
    double inv = 1.0 / sqrt(var + (double)EPSF);
    scale[c] = (float)((double)g[c] * inv);
    shift[c] = (float)((double)beta[c] - mu * (double)g[c] * inv);
}

// ---------------------------------------------------------------------------
// Graph: degree count, dinv, CSR build
// ---------------------------------------------------------------------------
__global__ __launch_bounds__(256) void count_deg(const int* __restrict__ col,
                                                 int* __restrict__ cnt, int E) {
    int e = blockIdx.x * 256 + threadIdx.x;
    if (e < E) atomicAdd(&cnt[col[e]], 1);
}

__global__ __launch_bounds__(256) void dinv_kernel(const int* __restrict__ cnt,
                                                   float* __restrict__ dinv, int M) {
    int i = blockIdx.x * 256 + threadIdx.x;
    if (i < M) {
        double deg = (double)(cnt[i] + 1);   // +1 self loop
        dinv[i] = (float)(1.0 / sqrt(deg));
    }
}

__global__ __launch_bounds__(256) void fill_csr(const int* __restrict__ row,
                                                const int* __restrict__ col,
                                                const int* __restrict__ off,
                                                int* __restrict__ cur,
                                                int* __restrict__ csr, int E) {
    int e = blockIdx.x * 256 + threadIdx.x;
    if (e < E) {
        int c = col[e];
        int p = atomicAdd(&cur[c], 1);
        csr[off[c] + p] = row[e];
    }
}

// ---------------------------------------------------------------------------
// Scan (3-phase exclusive scan; also writes out[n] = total)
// ---------------------------------------------------------------------------
__device__ __forceinline__ int waveInclScan(int v, int lane) {
#pragma unroll
    for (int o = 1; o < 64; o <<= 1) {
        int u = __shfl_up(v, o, 64);
        if (lane >= o) v += u;
    }
    return v;
}

__global__ __launch_bounds__(1024) void scan_phase1(const int* __restrict__ in,
                                                    int* __restrict__ out,
                                                    int* __restrict__ bsum, int n) {
    int t = threadIdx.x;
    int g = blockIdx.x * 1024 + t;
    int lane = t & 63, wid = t >> 6;
    int v = (g < n) ? in[g] : 0;
    int incl = waveInclScan(v, lane);
    __shared__ int ws[16];
    if (lane == 63) ws[wid] = incl;
    __syncthreads();
    if (t < 16) {
        int x = ws[t];
#pragma unroll
        for (int o = 1; o < 16; o <<= 1) {
            int u = __shfl_up(x, o, 64);
            if (t >= o) x += u;
        }
        ws[t] = x;
    }
    __syncthreads();
    int pre = (wid > 0) ? ws[wid - 1] : 0;
    if (g < n) out[g] = pre + incl - v;
    if (t == 1023) bsum[blockIdx.x] = ws[15];
}

__global__ __launch_bounds__(1024) void scan_phase2(int* __restrict__ bsum, int B,
                                                    int* __restrict__ out, int n) {
    int t = threadIdx.x;
    int lane = t & 63, wid = t >> 6;
    int v = (t < B) ? bsum[t] : 0;
    int incl = waveInclScan(v, lane);
    __shared__ int ws[16];
    if (lane == 63) ws[wid] = incl;
    __syncthreads();
    if (t < 16) {
        int x = ws[t];
#pragma unroll
        for (int o = 1; o < 16; o <<= 1) {
            int u = __shfl_up(x, o, 64);
            if (t >= o) x += u;
        }
        ws[t] = x;
    }
    __syncthreads();
    int pre = (wid > 0) ? ws[wid - 1] : 0;
    int glob_incl = pre + incl;
    if (t < B) bsum[t] = glob_incl - v;   // exclusive
    if (t == B - 1) out[n] = glob_incl;   // grand total
}

__global__ __launch_bounds__(1024) void scan_phase3(int* __restrict__ out,
                                                    const int* __restrict__ bsum, int n) {
    int g = blockIdx.x * 1024 + threadIdx.x;
    if (g < n) out[g] += bsum[blockIdx.x];
}

// ---------------------------------------------------------------------------
// GCN aggregation v2: one WAVE per node (4 nodes / 256-thr block), float2 per
// lane, unroll-4 gathers for MLP. HWs is pre-scaled by dinv[src].
// OUT[i] = dinv[i]*( sum_src HWs[src] + HWs[i] ) + gcn_b
// ---------------------------------------------------------------------------
__global__ __launch_bounds__(256) void gcn_agg(const float* __restrict__ HWs,
                                               const int* __restrict__ off,
                                               const int* __restrict__ csr,
                                               const float* __restrict__ dinv,
                                               const float* __restrict__ gcn_b,
                                               float* __restrict__ OUT, int M) {
    int lane = threadIdx.x & 63;
    int i = blockIdx.x * 4 + (threadIdx.x >> 6);
    if (i >= M) return;
    const float2* H2 = (const float2*)HWs;
    int o0 = off[i], o1 = off[i + 1];
    float2 hv = H2[(size_t)i * 64 + lane];   // self loop term
    double ax = (double)hv.x, ay = (double)hv.y;
    int e = o0;
    for (; e + 4 <= o1; e += 4) {
        int s0 = csr[e], s1 = csr[e + 1], s2 = csr[e + 2], s3 = csr[e + 3];
        float2 v0 = H2[(size_t)s0 * 64 + lane];
        float2 v1 = H2[(size_t)s1 * 64 + lane];
        float2 v2 = H2[(size_t)s2 * 64 + lane];
        float2 v3 = H2[(size_t)s3 * 64 + lane];
        ax += (double)v0.x + (double)v1.x + (double)v2.x + (double)v3.x;
        ay += (double)v0.y + (double)v1.y + (double)v2.y + (double)v3.y;
    }
    for (; e < o1; e++) {
        float2 v = H2[(size_t)csr[e] * 64 + lane];
        ax += (double)v.x;
        ay += (double)v.y;
    }
    double di = (double)dinv[i];
    float2 ob = ((const float2*)gcn_b)[lane];
    float2 o;
    o.x = (float)(ax * di) + ob.x;
    o.y = (float)(ay * di) + ob.y;
    ((float2*)OUT)[(size_t)i * 64 + lane] = o;
}

// ---------------------------------------------------------------------------
// Score (BN2+ReLU on the fly) + orderable key + bucket histogram. Wave/row.
// ---------------------------------------------------------------------------
__global__ __launch_bounds__(256) void score_key(const float* __restrict__ Y2,
                                                 const float* __restrict__ sc,
                                                 const float* __restrict__ sh,
                                                 const float* __restrict__ w,
                                                 float* __restrict__ score,
                                                 unsigned* __restrict__ key,
                                                 int* __restrict__ bcnt, int M) {
    int lane = threadIdx.x & 63;
    int wid = threadIdx.x >> 6;
    int gw = blockIdx.x * 4 + wid;
    int nw = gridDim.x * 4;

    float w0 = w[lane], w1 = w[lane + 64];
    float sc0 = sc[lane], sh0 = sh[lane];
    float sc1 = sc[lane + 64], sh1 = sh[lane + 64];

    float nv = w0 * w0 + w1 * w1;
#pragma unroll
    for (int o = 32; o >= 1; o >>= 1) nv += __shfl_xor(nv, o, 64);
    float nrm = sqrtf(nv);

    for (int r = gw; r < M; r += nw) {
        float a = Y2[(size_t)r * 128 + lane];
        float b = Y2[(size_t)r * 128 + lane + 64];
        a = fmaxf(a * sc0 + sh0, 0.f);
        b = fmaxf(b * sc1 + sh1, 0.f);
        float v = a * w0 + b * w1;
#pragma unroll
        for (int o = 32; o >= 1; o >>= 1) v += __shfl_xor(v, o, 64);
        if (lane == 0) {
            float s = tanhf(v / nrm);
            score[r] = s;
            unsigned u = __float_as_uint(s);
            unsigned k = (u & 0x80000000u) ? ~u : (u | 0x80000000u);
            key[r] = k;
            atomicAdd(&bcnt[k >> 16], 1);
        }
    }
}

__global__ __launch_bounds__(256) void bucket_fill(const unsigned* __restrict__ key,
                                                   const int* __restrict__ boff,
                                                   int* __restrict__ bcur,
                                                   int* __restrict__ bmem, int M) {
    int i = blockIdx.x * 256 + threadIdx.x;
    if (i < M) {
        int b = key[i] >> 16;
        int p = atomicAdd(&bcur[b], 1);
        bmem[boff[b] + p] = i;
    }
}

__global__ __launch_bounds__(256) void rank_kernel(const unsigned* __restrict__ key,
                                                   const int* __restrict__ boff,
                                                   const int* __restrict__ bmem,
                                                   int* __restrict__ rank,
                                                   int* __restrict__ nidx, int M) {
    int i = blockIdx.x * 256 + threadIdx.x;
    if (i >= M) return;
    unsigned ki = key[i];
    int b = ki >> 16;
    int r = M - boff[b + 1];   // all keys in strictly-greater buckets
    int p0 = boff[b], p1 = boff[b + 1];
    for (int p = p0; p < p1; p++) {
        int j = bmem[p];
        unsigned kj = key[j];
        if (kj > ki || (kj == ki && j < i)) r++;
    }
    rank[i] = r;
    nidx[i] = (r < KTOP) ? r : -1;
}

// ---------------------------------------------------------------------------
// Output writers (d_out: [x_pool K*128 | ei_new 2E | batch_new K], all f32)
// ---------------------------------------------------------------------------
__global__ __launch_bounds__(128) void write_pool(const float* __restrict__ Y2,
                                                  const float* __restrict__ sc,
                                                  const float* __restrict__ sh,
                                                  const float* __restrict__ score,
                                                  const int* __restrict__ rank,
                                                  float* __restrict__ out0,
                                                  float* __restrict__ out2, int M) {
    int i = blockIdx.x;
    int c = threadIdx.x;
    int r = rank[i];
    if (r < KTOP) {
        float h = fmaxf(Y2[(size_t)i * 128 + c] * sc[c] + sh[c], 0.f);
        out0[(size_t)r * 128 + c] = h * score[i];
        if (c == 0) out2[r] = 0.0f;   // batch_new (batch is all zeros)
    }
}

__global__ __launch_bounds__(256) void write_edges(const int* __restrict__ row,
                                                   const int* __restrict__ col,
                                                   const int* __restrict__ nidx,
                                                   float* __restrict__ out1, int E) {
    int e = blockIdx.x * 256 + threadIdx.x;
    if (e < E) {
        int a = nidx[row[e]];
        int b = nidx[col[e]];
        bool keep = (a >= 0) && (b >= 0);
        out1[e] = keep ? (float)a : -1.0f;
        out1[E + e] = keep ? (float)b : -1.0f;
    }
}

// ---------------------------------------------------------------------------
extern "C" void kernel_launch(void* const* d_in, const int* in_sizes, int n_in,
                              void* d_out, int out_size, void* d_ws, size_t ws_size,
                              hipStream_t stream) {
    const float* x = (const float*)d_in[0];
    const int* ei = (const int*)d_in[1];
    const float* lin_w = (const float*)d_in[3];
    const float* lin_b = (const float*)d_in[4];
    const float* bn1_g = (const float*)d_in[5];
    const float* bn1_b = (const float*)d_in[6];
    const float* gcn_w = (const float*)d_in[7];
    const float* gcn_b = (const float*)d_in[8];
    const float* bn2_g = (const float*)d_in[9];
    const float* bn2_b = (const float*)d_in[10];
    const float* pool_w = (const float*)d_in[11];

    const int* e_row = ei;        // edge_index[0]
    const int* e_col = ei + EE;   // edge_index[1]

    char* ws = (char*)d_ws;
    size_t off_b = 0;
    auto alloc = [&](size_t bytes) -> void* {
        void* p = ws + off_b;
        off_b = (off_b + bytes + 255) & ~(size_t)255;
        return p;
    };
    float* y = (float*)alloc((size_t)NN * 128 * 4);     // gemm1 out, later gcn out (y2)
    float* hws = (float*)alloc((size_t)NN * 128 * 4);   // dinv-scaled h @ gcn_w
    int* cnt = (int*)alloc(NN * 4);
    int* cur = (int*)alloc(NN * 4);
    int* offs = (int*)alloc((NN + 1) * 4);
    float* dinv = (float*)alloc(NN * 4);
    int* csr = (int*)alloc((size_t)EE * 4);
    float* score = (float*)alloc(NN * 4);
    unsigned* key = (unsigned*)alloc(NN * 4);
    int* rank = (int*)alloc(NN * 4);
    int* nidx = (int*)alloc(NN * 4);
    int* bcnt = (int*)alloc(65536 * 4);
    int* boff = (int*)alloc((65536 + 1) * 4);
    int* bcur = (int*)alloc(65536 * 4);
    int* bmem = (int*)alloc(NN * 4);
    double* part = (double*)alloc((size_t)BN2_NB * 128 * 2 * 8);
    float* scale1 = (float*)alloc(128 * 4);
    float* shift1 = (float*)alloc(128 * 4);
    float* scale2 = (float*)alloc(128 * 4);
    float* shift2 = (float*)alloc(128 * 4);
    int* bsum = (int*)alloc(128 * 4);

    float* out0 = (float*)d_out;                       // x_pool [K,128]
    float* out1 = out0 + (size_t)KTOP * 128;           // ei_new [2,E]
    float* out2 = out1 + (size_t)2 * EE;               // batch_new [K]

    int gemm_grid = (NN + 127) / 128;                  // 391

    // ---- graph prep (independent of feature path) ----
    hipMemsetAsync(cnt, 0, NN * 4, stream);
    hipMemsetAsync(cur, 0, NN * 4, stream);
    hipMemsetAsync(bcnt, 0, 65536 * 4, stream);
    hipMemsetAsync(bcur, 0, 65536 * 4, stream);
    count_deg<<<(EE + 255) / 256, 256, 0, stream>>>(e_col, cnt, EE);
    dinv_kernel<<<(NN + 255) / 256, 256, 0, stream>>>(cnt, dinv, NN);
    {
        int B = (NN + 1023) / 1024;
        scan_phase1<<<B, 1024, 0, stream>>>(cnt, offs, bsum, NN);
        scan_phase2<<<1, 1024, 0, stream>>>(bsum, B, offs, NN);
        scan_phase3<<<B, 1024, 0, stream>>>(offs, bsum, NN);
    }
    fill_csr<<<(EE + 255) / 256, 256, 0, stream>>>(e_row, e_col, offs, cur, csr, EE);

    // ---- MLP: Linear (+ fused BN1 stats) ----
    gemm_bn_stats<<<gemm_grid, 256, 0, stream>>>(x, lin_w, lin_b, y, part, NN);
    bn_finalize<<<1, 128, 0, stream>>>(part, gemm_grid, bn1_g, bn1_b, scale1, shift1, NN);

    // ---- GCN: (BN1+ReLU fused) @ gcn_w, pre-scaled by dinv ----
    gemm_bn_apply<<<gemm_grid, 256, 0, stream>>>(y, gcn_w, scale1, shift1, dinv, hws, NN);
    gcn_agg<<<(NN + 3) / 4, 256, 0, stream>>>(hws, offs, csr, dinv, gcn_b, y, NN);

    // ---- BN2 stats ----
    bn_stats<<<BN2_NB, 128, 0, stream>>>(y, part, NN);
    bn_finalize<<<1, 128, 0, stream>>>(part, BN2_NB, bn2_g, bn2_b, scale2, shift2, NN);

    // ---- TopK pooling (BN2+ReLU fused into consumers) ----
    score_key<<<512, 256, 0, stream>>>(y, scale2, shift2, pool_w, score, key, bcnt, NN);
    {
        int B = 65536 / 1024;
        scan_phase1<<<B, 1024, 0, stream>>>(bcnt, boff, bsum, 65536);
        scan_phase2<<<1, 1024, 0, stream>>>(bsum, B, boff, 65536);
        scan_phase3<<<B, 1024, 0, stream>>>(boff, bsum, 65536);
    }
    bucket_fill<<<(NN + 255) / 256, 256, 0, stream>>>(key, boff, bcur, bmem, NN);
    rank_kernel<<<(NN + 255) / 256, 256, 0, stream>>>(key, boff, bmem, rank, nidx, NN);

    // ---- outputs ----
    write_pool<<<NN, 128, 0, stream>>>(y, scale2, shift2, score, rank, out0, out2, NN);
    write_edges<<<(EE + 255) / 256, 256, 0, stream>>>(e_row, e_col, nidx, out1, EE);
}

// Round 4
// 381.664 us; speedup vs baseline: 1.8091x; 1.7607x over previous
//
#include <hip/hip_runtime.h>
#include <hip/hip_bf16.h>

#define NN 50000
#define EE 800000
#define KTOP 25000
#define EPSF 1e-5

// ---------------------------------------------------------------------------
// GEMM1: Y[M,128] = A[M,128] @ W[128,128] + bias, fused per-block BN partials.
// block 256 threads, tile 128x128, 8x8 micro-tile. part[bid][c] = (sum,sumsq)
// ---------------------------------------------------------------------------
__global__ __launch_bounds__(256, 2) void gemm_bn_stats(const float* __restrict__ A,
                                                        const float* __restrict__ W,
                                                        const float* __restrict__ bias,
                                                        float* __restrict__ Y,
                                                        double* __restrict__ part, int M) {
    __shared__ float Bs[128][128];   // 64 KiB: W, [k][n]
    __shared__ float As[32][128];    // 16 KiB: A-chunk transposed, [k][row]
    int t = threadIdx.x;
    int bm = blockIdx.x * 128;

    const float4* W4 = (const float4*)W;
    float4* Bs4 = (float4*)Bs;
#pragma unroll
    for (int i = 0; i < 16; i++) Bs4[t + i * 256] = W4[t + i * 256];

    float acc[8][8];
#pragma unroll
    for (int i = 0; i < 8; i++)
#pragma unroll
        for (int j = 0; j < 8; j++) acc[i][j] = 0.f;

    int ty = t >> 4;   // 0..15 row group
    int tx = t & 15;   // 0..15 col group

    for (int kc = 0; kc < 4; kc++) {
        __syncthreads();
#pragma unroll
        for (int i = 0; i < 4; i++) {
            int f4 = t + i * 256;
            int r = f4 >> 3, k4 = f4 & 7;
            int row = bm + r;
            float4 v = make_float4(0.f, 0.f, 0.f, 0.f);
            if (row < M) v = *(const float4*)&A[(size_t)row * 128 + kc * 32 + k4 * 4];
            As[k4 * 4 + 0][r] = v.x;
            As[k4 * 4 + 1][r] = v.y;
            As[k4 * 4 + 2][r] = v.z;
            As[k4 * 4 + 3][r] = v.w;
        }
        __syncthreads();
#pragma unroll
        for (int kk = 0; kk < 32; kk++) {
            float4 a0 = *(float4*)&As[kk][ty * 8];
            float4 a1 = *(float4*)&As[kk][ty * 8 + 4];
            float4 b0 = *(float4*)&Bs[kc * 32 + kk][tx * 8];
            float4 b1 = *(float4*)&Bs[kc * 32 + kk][tx * 8 + 4];
            float av[8] = {a0.x, a0.y, a0.z, a0.w, a1.x, a1.y, a1.z, a1.w};
            float bv[8] = {b0.x, b0.y, b0.z, b0.w, b1.x, b1.y, b1.z, b1.w};
#pragma unroll
            for (int i = 0; i < 8; i++)
#pragma unroll
                for (int j = 0; j < 8; j++) acc[i][j] += av[i] * bv[j];
        }
    }

    // epilogue: write Y and per-thread channel partials over its 8 rows
    float s[8], s2[8];
#pragma unroll
    for (int j = 0; j < 8; j++) { s[j] = 0.f; s2[j] = 0.f; }
#pragma unroll
    for (int i = 0; i < 8; i++) {
        int row = bm + ty * 8 + i;
        if (row < M) {
#pragma unroll
            for (int j = 0; j < 8; j++) {
                float yv = acc[i][j] + bias[tx * 8 + j];
                Y[(size_t)row * 128 + tx * 8 + j] = yv;
                s[j] += yv;
                s2[j] += yv * yv;
            }
        }
    }
    __syncthreads();                       // As no longer needed
    float2* Sred = (float2*)As;            // [16][128] = 16 KiB exactly
#pragma unroll
    for (int j = 0; j < 8; j++) Sred[ty * 128 + tx * 8 + j] = make_float2(s[j], s2[j]);
    __syncthreads();
    if (t < 128) {
        double S = 0.0, S2 = 0.0;
#pragma unroll
        for (int r = 0; r < 16; r++) {
            float2 v = Sred[r * 128 + t];
            S += (double)v.x;
            S2 += (double)v.y;
        }
        part[((size_t)blockIdx.x * 128 + t) * 2 + 0] = S;
        part[((size_t)blockIdx.x * 128 + t) * 2 + 1] = S2;
    }
}

// ---------------------------------------------------------------------------
// GEMM2: HWs[M,128] = dinv[row] * ( relu(bn1(Yin)) @ W ).  BN1 applied on the
// fly during A-staging; dinv scaling in epilogue.
// ---------------------------------------------------------------------------
__global__ __launch_bounds__(256, 2) void gemm_bn_apply(const float* __restrict__ Yin,
                                                        const float* __restrict__ W,
                                                        const float* __restrict__ sc,
                                                        const float* __restrict__ sh,
                                                        const float* __restrict__ dinv,
                                                        float* __restrict__ HWs, int M) {
    __shared__ float Bs[128][128];
    __shared__ float As[32][128];
    int t = threadIdx.x;
    int bm = blockIdx.x * 128;

    const float4* W4 = (const float4*)W;
    float4* Bs4 = (float4*)Bs;
#pragma unroll
    for (int i = 0; i < 16; i++) Bs4[t + i * 256] = W4[t + i * 256];

    float acc[8][8];
#pragma unroll
    for (int i = 0; i < 8; i++)
#pragma unroll
        for (int j = 0; j < 8; j++) acc[i][j] = 0.f;

    int ty = t >> 4;
    int tx = t & 15;

    for (int kc = 0; kc < 4; kc++) {
        __syncthreads();
#pragma unroll
        for (int i = 0; i < 4; i++) {
            int f4 = t + i * 256;
            int r = f4 >> 3, k4 = f4 & 7;
            int row = bm + r;
            int col = kc * 32 + k4 * 4;
            float4 v = make_float4(0.f, 0.f, 0.f, 0.f);
            if (row < M) {
                float4 y = *(const float4*)&Yin[(size_t)row * 128 + col];
                float4 scv = *(const float4*)&sc[col];
                float4 shv = *(const float4*)&sh[col];
                v.x = fmaxf(y.x * scv.x + shv.x, 0.f);
                v.y = fmaxf(y.y * scv.y + shv.y, 0.f);
                v.z = fmaxf(y.z * scv.z + shv.z, 0.f);
                v.w = fmaxf(y.w * scv.w + shv.w, 0.f);
            }
            As[k4 * 4 + 0][r] = v.x;
            As[k4 * 4 + 1][r] = v.y;
            As[k4 * 4 + 2][r] = v.z;
            As[k4 * 4 + 3][r] = v.w;
        }
        __syncthreads();
#pragma unroll
        for (int kk = 0; kk < 32; kk++) {
            float4 a0 = *(float4*)&As[kk][ty * 8];
            float4 a1 = *(float4*)&As[kk][ty * 8 + 4];
            float4 b0 = *(float4*)&Bs[kc * 32 + kk][tx * 8];
            float4 b1 = *(float4*)&Bs[kc * 32 + kk][tx * 8 + 4];
            float av[8] = {a0.x, a0.y, a0.z, a0.w, a1.x, a1.y, a1.z, a1.w};
            float bv[8] = {b0.x, b0.y, b0.z, b0.w, b1.x, b1.y, b1.z, b1.w};
#pragma unroll
            for (int i = 0; i < 8; i++)
#pragma unroll
                for (int j = 0; j < 8; j++) acc[i][j] += av[i] * bv[j];
        }
    }
#pragma unroll
    for (int i = 0; i < 8; i++) {
        int row = bm + ty * 8 + i;
        if (row < M) {
            float di = dinv[row];
#pragma unroll
            for (int j = 0; j < 8; j++)
                HWs[(size_t)row * 128 + tx * 8 + j] = acc[i][j] * di;
        }
    }
}

// ---------------------------------------------------------------------------
// BN stats (for gcn output): 64 rows/block, unroll-4, f64 partials
// ---------------------------------------------------------------------------
#define BN2_ROWS 64
#define BN2_NB ((NN + BN2_ROWS - 1) / BN2_ROWS)   // 782

__global__ __launch_bounds__(128) void bn_stats(const float* __restrict__ Y,
                                                double* __restrict__ part, int M) {
    int c = threadIdx.x;
    int b = blockIdx.x;
    int r0 = b * BN2_ROWS;
    int r1 = min(M, r0 + BN2_ROWS);
    double s = 0.0, s2 = 0.0;
    int r = r0;
    for (; r + 4 <= r1; r += 4) {
        float v0 = Y[(size_t)r * 128 + c];
        float v1 = Y[(size_t)(r + 1) * 128 + c];
        float v2 = Y[(size_t)(r + 2) * 128 + c];
        float v3 = Y[(size_t)(r + 3) * 128 + c];
        s += (double)v0 + (double)v1 + (double)v2 + (double)v3;
        s2 += (double)v0 * v0 + (double)v1 * v1 + (double)v2 * v2 + (double)v3 * v3;
    }
    for (; r < r1; r++) {
        float v = Y[(size_t)r * 128 + c];
        s += (double)v;
        s2 += (double)v * v;
    }
    part[((size_t)b * 128 + c) * 2 + 0] = s;
    part[((size_t)b * 128 + c) * 2 + 1] = s2;
}

// ---------------------------------------------------------------------------
// BN finalize v2: PARALLEL — one block per channel, 256 threads, LDS f64 tree.
// (v1 was a single 128-thread block looping nb serially: 201 us, 60% of total)
// ---------------------------------------------------------------------------
__global__ __launch_bounds__(256) void bn_finalize(const double* __restrict__ part, int nb,
                                                   const float* __restrict__ g,
                                                   const float* __restrict__ beta,
                                                   float* __restrict__ scale,
                                                   float* __restrict__ shift, int M) {
    int c = blockIdx.x;
    int t = threadIdx.x;
    double s = 0.0, s2 = 0.0;
    for (int b = t; b < nb; b += 256) {
        s += part[((size_t)b * 128 + c) * 2 + 0];
        s2 += part[((size_t)b * 128 + c) * 2 + 1];
    }
    __shared__ double sd[256], sd2[256];
    sd[t] = s;
    sd2[t] = s2;
    __syncthreads();
#pragma unroll
    for (int o = 128; o > 0; o >>= 1) {
        if (t < o) {
            sd[t] += sd[t + o];
            sd2[t] += sd2[t + o];
        }
        __syncthreads();
    }
    if (t == 0) {
        double S = sd[0], S2 = sd2[0];
        double mu = S / (double)M;
        double var = S2 / (double)M - mu * mu;
        double inv = 1.0 / sqrt(var + (double)EPSF);
        scale[c] = (float)((double)g[c] * inv);
        shift[c] = (float)((double)beta[c] - mu * (double)g[c] * inv);
    }
}

// ---------------------------------------------------------------------------
// Graph: degree count, dinv, CSR build
// ---------------------------------------------------------------------------
__global__ __launch_bounds__(256) void count_deg(const int* __restrict__ col,
                                                 int* __restrict__ cnt, int E) {
    int e = blockIdx.x * 256 + threadIdx.x;
    if (e < E) atomicAdd(&cnt[col[e]], 1);
}

__global__ __launch_bounds__(256) void dinv_kernel(const int* __restrict__ cnt,
                                                   float* __restrict__ dinv, int M) {
    int i = blockIdx.x * 256 + threadIdx.x;
    if (i < M) {
        double deg = (double)(cnt[i] + 1);   // +1 self loop
        dinv[i] = (float)(1.0 / sqrt(deg));
    }
}

__global__ __launch_bounds__(256) void fill_csr(const int* __restrict__ row,
                                                const int* __restrict__ col,
                                                const int* __restrict__ off,
                                                int* __restrict__ cur,
                                                int* __restrict__ csr, int E) {
    int e = blockIdx.x * 256 + threadIdx.x;
    if (e < E) {
        int c = col[e];
        int p = atomicAdd(&cur[c], 1);
        csr[off[c] + p] = row[e];
    }
}

// ---------------------------------------------------------------------------
// Scan (3-phase exclusive scan; also writes out[n] = total)
// ---------------------------------------------------------------------------
__device__ __forceinline__ int waveInclScan(int v, int lane) {
#pragma unroll
    for (int o = 1; o < 64; o <<= 1) {
        int u = __shfl_up(v, o, 64);
        if (lane >= o) v += u;
    }
    return v;
}

__global__ __launch_bounds__(1024) void scan_phase1(const int* __restrict__ in,
                                                    int* __restrict__ out,
                                                    int* __restrict__ bsum, int n) {
    int t = threadIdx.x;
    int g = blockIdx.x * 1024 + t;
    int lane = t & 63, wid = t >> 6;
    int v = (g < n) ? in[g] : 0;
    int incl = waveInclScan(v, lane);
    __shared__ int ws[16];
    if (lane == 63) ws[wid] = incl;
    __syncthreads();
    if (t < 16) {
        int x = ws[t];
#pragma unroll
        for (int o = 1; o < 16; o <<= 1) {
            int u = __shfl_up(x, o, 64);
            if (t >= o) x += u;
        }
        ws[t] = x;
    }
    __syncthreads();
    int pre = (wid > 0) ? ws[wid - 1] : 0;
    if (g < n) out[g] = pre + incl - v;
    if (t == 1023) bsum[blockIdx.x] = ws[15];
}

__global__ __launch_bounds__(1024) void scan_phase2(int* __restrict__ bsum, int B,
                                                    int* __restrict__ out, int n) {
    int t = threadIdx.x;
    int lane = t & 63, wid = t >> 6;
    int v = (t < B) ? bsum[t] : 0;
    int incl = waveInclScan(v, lane);
    __shared__ int ws[16];
    if (lane == 63) ws[wid] = incl;
    __syncthreads();
    if (t < 16) {
        int x = ws[t];
#pragma unroll
        for (int o = 1; o < 16; o <<= 1) {
            int u = __shfl_up(x, o, 64);
            if (t >= o) x += u;
        }
        ws[t] = x;
    }
    __syncthreads();
    int pre = (wid > 0) ? ws[wid - 1] : 0;
    int glob_incl = pre + incl;
    if (t < B) bsum[t] = glob_incl - v;   // exclusive
    if (t == B - 1) out[n] = glob_incl;   // grand total
}

__global__ __launch_bounds__(1024) void scan_phase3(int* __restrict__ out,
                                                    const int* __restrict__ bsum, int n) {
    int g = blockIdx.x * 1024 + threadIdx.x;
    if (g < n) out[g] += bsum[blockIdx.x];
}

// ---------------------------------------------------------------------------
// GCN aggregation: one WAVE per node (4 nodes / 256-thr block), float2 per
// lane, unroll-4 gathers for MLP. HWs is pre-scaled by dinv[src].
// OUT[i] = dinv[i]*( sum_src HWs[src] + HWs[i] ) + gcn_b
// ---------------------------------------------------------------------------
__global__ __launch_bounds__(256) void gcn_agg(const float* __restrict__ HWs,
                                               const int* __restrict__ off,
                                               const int* __restrict__ csr,
                                               const float* __restrict__ dinv,
                                               const float* __restrict__ gcn_b,
                                               float* __restrict__ OUT, int M) {
    int lane = threadIdx.x & 63;
    int i = blockIdx.x * 4 + (threadIdx.x >> 6);
    if (i >= M) return;
    const float2* H2 = (const float2*)HWs;
    int o0 = off[i], o1 = off[i + 1];
    float2 hv = H2[(size_t)i * 64 + lane];   // self loop term
    double ax = (double)hv.x, ay = (double)hv.y;
    int e = o0;
    for (; e + 4 <= o1; e += 4) {
        int s0 = csr[e], s1 = csr[e + 1], s2 = csr[e + 2], s3 = csr[e + 3];
        float2 v0 = H2[(size_t)s0 * 64 + lane];
        float2 v1 = H2[(size_t)s1 * 64 + lane];
        float2 v2 = H2[(size_t)s2 * 64 + lane];
        float2 v3 = H2[(size_t)s3 * 64 + lane];
        ax += (double)v0.x + (double)v1.x + (double)v2.x + (double)v3.x;
        ay += (double)v0.y + (double)v1.y + (double)v2.y + (double)v3.y;
    }
    for (; e < o1; e++) {
        float2 v = H2[(size_t)csr[e] * 64 + lane];
        ax += (double)v.x;
        ay += (double)v.y;
    }
    double di = (double)dinv[i];
    float2 ob = ((const float2*)gcn_b)[lane];
    float2 o;
    o.x = (float)(ax * di) + ob.x;
    o.y = (float)(ay * di) + ob.y;
    ((float2*)OUT)[(size_t)i * 64 + lane] = o;
}

// ---------------------------------------------------------------------------
// Score (BN2+ReLU on the fly) + orderable key + bucket histogram. Wave/row.
// ---------------------------------------------------------------------------
__global__ __launch_bounds__(256) void score_key(const float* __restrict__ Y2,
                                                 const float* __restrict__ sc,
                                                 const float* __restrict__ sh,
                                                 const float* __restrict__ w,
                                                 float* __restrict__ score,
                                                 unsigned* __restrict__ key,
                                                 int* __restrict__ bcnt, int M) {
    int lane = threadIdx.x & 63;
    int wid = threadIdx.x >> 6;
    int gw = blockIdx.x * 4 + wid;
    int nw = gridDim.x * 4;

    float w0 = w[lane], w1 = w[lane + 64];
    float sc0 = sc[lane], sh0 = sh[lane];
    float sc1 = sc[lane + 64], sh1 = sh[lane + 64];

    float nv = w0 * w0 + w1 * w1;
#pragma unroll
    for (int o = 32; o >= 1; o >>= 1) nv += __shfl_xor(nv, o, 64);
    float nrm = sqrtf(nv);

    for (int r = gw; r < M; r += nw) {
        float a = Y2[(size_t)r * 128 + lane];
        float b = Y2[(size_t)r * 128 + lane + 64];
        a = fmaxf(a * sc0 + sh0, 0.f);
        b = fmaxf(b * sc1 + sh1, 0.f);
        float v = a * w0 + b * w1;
#pragma unroll
        for (int o = 32; o >= 1; o >>= 1) v += __shfl_xor(v, o, 64);
        if (lane == 0) {
            float s = tanhf(v / nrm);
            score[r] = s;
            unsigned u = __float_as_uint(s);
            unsigned k = (u & 0x80000000u) ? ~u : (u | 0x80000000u);
            key[r] = k;
            atomicAdd(&bcnt[k >> 16], 1);
        }
    }
}

__global__ __launch_bounds__(256) void bucket_fill(const unsigned* __restrict__ key,
                                                   const int* __restrict__ boff,
                                                   int* __restrict__ bcur,
                                                   int* __restrict__ bmem, int M) {
    int i = blockIdx.x * 256 + threadIdx.x;
    if (i < M) {
        int b = key[i] >> 16;
        int p = atomicAdd(&bcur[b], 1);
        bmem[boff[b] + p] = i;
    }
}

__global__ __launch_bounds__(256) void rank_kernel(const unsigned* __restrict__ key,
                                                   const int* __restrict__ boff,
                                                   const int* __restrict__ bmem,
                                                   int* __restrict__ rank,
                                                   int* __restrict__ nidx, int M) {
    int i = blockIdx.x * 256 + threadIdx.x;
    if (i >= M) return;
    unsigned ki = key[i];
    int b = ki >> 16;
    int r = M - boff[b + 1];   // all keys in strictly-greater buckets
    int p0 = boff[b], p1 = boff[b + 1];
    for (int p = p0; p < p1; p++) {
        int j = bmem[p];
        unsigned kj = key[j];
        if (kj > ki || (kj == ki && j < i)) r++;
    }
    rank[i] = r;
    nidx[i] = (r < KTOP) ? r : -1;
}

// ---------------------------------------------------------------------------
// Output writers (d_out: [x_pool K*128 | ei_new 2E | batch_new K], all f32)
// ---------------------------------------------------------------------------
__global__ __launch_bounds__(128) void write_pool(const float* __restrict__ Y2,
                                                  const float* __restrict__ sc,
                                                  const float* __restrict__ sh,
                                                  const float* __restrict__ score,
                                                  const int* __restrict__ rank,
                                                  float* __restrict__ out0,
                                                  float* __restrict__ out2, int M) {
    int i = blockIdx.x;
    int c = threadIdx.x;
    int r = rank[i];
    if (r < KTOP) {
        float h = fmaxf(Y2[(size_t)i * 128 + c] * sc[c] + sh[c], 0.f);
        out0[(size_t)r * 128 + c] = h * score[i];
        if (c == 0) out2[r] = 0.0f;   // batch_new (batch is all zeros)
    }
}

__global__ __launch_bounds__(256) void write_edges(const int* __restrict__ row,
                                                   const int* __restrict__ col,
                                                   const int* __restrict__ nidx,
                                                   float* __restrict__ out1, int E) {
    int e = blockIdx.x * 256 + threadIdx.x;
    if (e < E) {
        int a = nidx[row[e]];
        int b = nidx[col[e]];
        bool keep = (a >= 0) && (b >= 0);
        out1[e] = keep ? (float)a : -1.0f;
        out1[E + e] = keep ? (float)b : -1.0f;
    }
}

// ---------------------------------------------------------------------------
extern "C" void kernel_launch(void* const* d_in, const int* in_sizes, int n_in,
                              void* d_out, int out_size, void* d_ws, size_t ws_size,
                              hipStream_t stream) {
    const float* x = (const float*)d_in[0];
    const int* ei = (const int*)d_in[1];
    const float* lin_w = (const float*)d_in[3];
    const float* lin_b = (const float*)d_in[4];
    const float* bn1_g = (const float*)d_in[5];
    const float* bn1_b = (const float*)d_in[6];
    const float* gcn_w = (const float*)d_in[7];
    const float* gcn_b = (const float*)d_in[8];
    const float* bn2_g = (const float*)d_in[9];
    const float* bn2_b = (const float*)d_in[10];
    const float* pool_w = (const float*)d_in[11];

    const int* e_row = ei;        // edge_index[0]
    const int* e_col = ei + EE;   // edge_index[1]

    char* ws = (char*)d_ws;
    size_t off_b = 0;
    auto alloc = [&](size_t bytes) -> void* {
        void* p = ws + off_b;
        off_b = (off_b + bytes + 255) & ~(size_t)255;
        return p;
    };
    float* y = (float*)alloc((size_t)NN * 128 * 4);     // gemm1 out, later gcn out (y2)
    float* hws = (float*)alloc((size_t)NN * 128 * 4);   // dinv-scaled h @ gcn_w
    int* cnt = (int*)alloc(NN * 4);
    int* cur = (int*)alloc(NN * 4);
    int* offs = (int*)alloc((NN + 1) * 4);
    float* dinv = (float*)alloc(NN * 4);
    int* csr = (int*)alloc((size_t)EE * 4);
    float* score = (float*)alloc(NN * 4);
    unsigned* key = (unsigned*)alloc(NN * 4);
    int* rank = (int*)alloc(NN * 4);
    int* nidx = (int*)alloc(NN * 4);
    int* bcnt = (int*)alloc(65536 * 4);
    int* boff = (int*)alloc((65536 + 1) * 4);
    int* bcur = (int*)alloc(65536 * 4);
    int* bmem = (int*)alloc(NN * 4);
    double* part = (double*)alloc((size_t)BN2_NB * 128 * 2 * 8);
    float* scale1 = (float*)alloc(128 * 4);
    float* shift1 = (float*)alloc(128 * 4);
    float* scale2 = (float*)alloc(128 * 4);
    float* shift2 = (float*)alloc(128 * 4);
    int* bsum = (int*)alloc(128 * 4);

    float* out0 = (float*)d_out;                       // x_pool [K,128]
    float* out1 = out0 + (size_t)KTOP * 128;           // ei_new [2,E]
    float* out2 = out1 + (size_t)2 * EE;               // batch_new [K]

    int gemm_grid = (NN + 127) / 128;                  // 391

    // ---- graph prep (independent of feature path) ----
    hipMemsetAsync(cnt, 0, NN * 4, stream);
    hipMemsetAsync(cur, 0, NN * 4, stream);
    hipMemsetAsync(bcnt, 0, 65536 * 4, stream);
    hipMemsetAsync(bcur, 0, 65536 * 4, stream);
    count_deg<<<(EE + 255) / 256, 256, 0, stream>>>(e_col, cnt, EE);
    dinv_kernel<<<(NN + 255) / 256, 256, 0, stream>>>(cnt, dinv, NN);
    {
        int B = (NN + 1023) / 1024;
        scan_phase1<<<B, 1024, 0, stream>>>(cnt, offs, bsum, NN);
        scan_phase2<<<1, 1024, 0, stream>>>(bsum, B, offs, NN);
        scan_phase3<<<B, 1024, 0, stream>>>(offs, bsum, NN);
    }
    fill_csr<<<(EE + 255) / 256, 256, 0, stream>>>(e_row, e_col, offs, cur, csr, EE);

    // ---- MLP: Linear (+ fused BN1 stats) ----
    gemm_bn_stats<<<gemm_grid, 256, 0, stream>>>(x, lin_w, lin_b, y, part, NN);
    bn_finalize<<<128, 256, 0, stream>>>(part, gemm_grid, bn1_g, bn1_b, scale1, shift1, NN);

    // ---- GCN: (BN1+ReLU fused) @ gcn_w, pre-scaled by dinv ----
    gemm_bn_apply<<<gemm_grid, 256, 0, stream>>>(y, gcn_w, scale1, shift1, dinv, hws, NN);
    gcn_agg<<<(NN + 3) / 4, 256, 0, stream>>>(hws, offs, csr, dinv, gcn_b, y, NN);

    // ---- BN2 stats ----
    bn_stats<<<BN2_NB, 128, 0, stream>>>(y, part, NN);
    bn_finalize<<<128, 256, 0, stream>>>(part, BN2_NB, bn2_g, bn2_b, scale2, shift2, NN);

    // ---- TopK pooling (BN2+ReLU fused into consumers) ----
    score_key<<<512, 256, 0, stream>>>(y, scale2, shift2, pool_w, score, key, bcnt, NN);
    {
        int B = 65536 / 1024;
        scan_phase1<<<B, 1024, 0, stream>>>(bcnt, boff, bsum, 65536);
        scan_phase2<<<1, 1024, 0, stream>>>(bsum, B, boff, 65536);
        scan_phase3<<<B, 1024, 0, stream>>>(boff, bsum, 65536);
    }
    bucket_fill<<<(NN + 255) / 256, 256, 0, stream>>>(key, boff, bcur, bmem, NN);
    rank_kernel<<<(NN + 255) / 256, 256, 0, stream>>>(key, boff, bmem, rank, nidx, NN);

    // ---- outputs ----
    write_pool<<<NN, 128, 0, stream>>>(y, scale2, shift2, score, rank, out0, out2, NN);
    write_edges<<<(EE + 255) / 256, 256, 0, stream>>>(e_row, e_col, nidx, out1, EE);
}

// Round 5
// 363.016 us; speedup vs baseline: 1.9020x; 1.0514x over previous
//
#include <hip/hip_runtime.h>
#include <hip/hip_bf16.h>

#define NN 50000
#define EE 800000
#define KTOP 25000
#define EPSF 1e-5

// ---------------------------------------------------------------------------
// GEMM1: Y[M,128] = A[M,128] @ W[128,128] + bias, fused per-block BN partials.
// block 256 threads, tile 128x128, 8x8 micro-tile (B cols split tx*4 / 64+tx*4
// for conflict-free ds_read_b128). As padded [32][132] (staging-write 8->2way).
// ---------------------------------------------------------------------------
__global__ __launch_bounds__(256, 2) void gemm_bn_stats(const float* __restrict__ A,
                                                        const float* __restrict__ W,
                                                        const float* __restrict__ bias,
                                                        float* __restrict__ Y,
                                                        double* __restrict__ part, int M) {
    __shared__ float Bs[128][128];   // 64 KiB: W, [k][n]
    __shared__ float As[32][132];    // padded: A-chunk transposed, [k][row]
    int t = threadIdx.x;
    int bm = blockIdx.x * 128;

    const float4* W4 = (const float4*)W;
    float4* Bs4 = (float4*)Bs;
#pragma unroll
    for (int i = 0; i < 16; i++) Bs4[t + i * 256] = W4[t + i * 256];

    float acc[8][8];
#pragma unroll
    for (int i = 0; i < 8; i++)
#pragma unroll
        for (int j = 0; j < 8; j++) acc[i][j] = 0.f;

    int ty = t >> 4;   // 0..15 row group (8 rows each)
    int tx = t & 15;   // 0..15 col group (cols tx*4..+4 and 64+tx*4..+4)

    for (int kc = 0; kc < 4; kc++) {
        __syncthreads();
#pragma unroll
        for (int i = 0; i < 4; i++) {
            int f4 = t + i * 256;
            int r = f4 >> 3, k4 = f4 & 7;
            int row = bm + r;
            float4 v = make_float4(0.f, 0.f, 0.f, 0.f);
            if (row < M) v = *(const float4*)&A[(size_t)row * 128 + kc * 32 + k4 * 4];
            As[k4 * 4 + 0][r] = v.x;
            As[k4 * 4 + 1][r] = v.y;
            As[k4 * 4 + 2][r] = v.z;
            As[k4 * 4 + 3][r] = v.w;
        }
        __syncthreads();
#pragma unroll
        for (int kk = 0; kk < 32; kk++) {
            float4 a0 = *(float4*)&As[kk][ty * 8];
            float4 a1 = *(float4*)&As[kk][ty * 8 + 4];
            float4 b0 = *(float4*)&Bs[kc * 32 + kk][tx * 4];
            float4 b1 = *(float4*)&Bs[kc * 32 + kk][64 + tx * 4];
            float av[8] = {a0.x, a0.y, a0.z, a0.w, a1.x, a1.y, a1.z, a1.w};
            float bv[8] = {b0.x, b0.y, b0.z, b0.w, b1.x, b1.y, b1.z, b1.w};
#pragma unroll
            for (int i = 0; i < 8; i++)
#pragma unroll
                for (int j = 0; j < 8; j++) acc[i][j] += av[i] * bv[j];
        }
    }

    float4 bb0 = *(const float4*)&bias[tx * 4];
    float4 bb1 = *(const float4*)&bias[64 + tx * 4];
    float s[8], s2[8];
#pragma unroll
    for (int j = 0; j < 8; j++) { s[j] = 0.f; s2[j] = 0.f; }
#pragma unroll
    for (int i = 0; i < 8; i++) {
        int row = bm + ty * 8 + i;
        if (row < M) {
            float4 y0, y1;
            y0.x = acc[i][0] + bb0.x; y0.y = acc[i][1] + bb0.y;
            y0.z = acc[i][2] + bb0.z; y0.w = acc[i][3] + bb0.w;
            y1.x = acc[i][4] + bb1.x; y1.y = acc[i][5] + bb1.y;
            y1.z = acc[i][6] + bb1.z; y1.w = acc[i][7] + bb1.w;
            *(float4*)&Y[(size_t)row * 128 + tx * 4] = y0;
            *(float4*)&Y[(size_t)row * 128 + 64 + tx * 4] = y1;
            s[0] += y0.x; s2[0] += y0.x * y0.x;
            s[1] += y0.y; s2[1] += y0.y * y0.y;
            s[2] += y0.z; s2[2] += y0.z * y0.z;
            s[3] += y0.w; s2[3] += y0.w * y0.w;
            s[4] += y1.x; s2[4] += y1.x * y1.x;
            s[5] += y1.y; s2[5] += y1.y * y1.y;
            s[6] += y1.z; s2[6] += y1.z * y1.z;
            s[7] += y1.w; s2[7] += y1.w * y1.w;
        }
    }
    __syncthreads();                       // As no longer needed
    float2* Sred = (float2*)As;            // [16][128] fits in padded As
#pragma unroll
    for (int j = 0; j < 8; j++) {
        int col = (j < 4) ? (tx * 4 + j) : (64 + tx * 4 + j - 4);
        Sred[ty * 128 + col] = make_float2(s[j], s2[j]);
    }
    __syncthreads();
    if (t < 128) {
        double S = 0.0, S2 = 0.0;
#pragma unroll
        for (int r = 0; r < 16; r++) {
            float2 v = Sred[r * 128 + t];
            S += (double)v.x;
            S2 += (double)v.y;
        }
        part[((size_t)blockIdx.x * 128 + t) * 2 + 0] = S;
        part[((size_t)blockIdx.x * 128 + t) * 2 + 1] = S2;
    }
}

// ---------------------------------------------------------------------------
// GEMM2: HWs[M,128] = dinv[row] * ( relu(bn1(Yin)) @ W ).  BN1 applied on the
// fly during A-staging; dinv scaling in epilogue. Same conflict-free layout.
// ---------------------------------------------------------------------------
__global__ __launch_bounds__(256, 2) void gemm_bn_apply(const float* __restrict__ Yin,
                                                        const float* __restrict__ W,
                                                        const float* __restrict__ sc,
                                                        const float* __restrict__ sh,
                                                        const float* __restrict__ dinv,
                                                        float* __restrict__ HWs, int M) {
    __shared__ float Bs[128][128];
    __shared__ float As[32][132];
    int t = threadIdx.x;
    int bm = blockIdx.x * 128;

    const float4* W4 = (const float4*)W;
    float4* Bs4 = (float4*)Bs;
#pragma unroll
    for (int i = 0; i < 16; i++) Bs4[t + i * 256] = W4[t + i * 256];

    float acc[8][8];
#pragma unroll
    for (int i = 0; i < 8; i++)
#pragma unroll
        for (int j = 0; j < 8; j++) acc[i][j] = 0.f;

    int ty = t >> 4;
    int tx = t & 15;

    for (int kc = 0; kc < 4; kc++) {
        __syncthreads();
#pragma unroll
        for (int i = 0; i < 4; i++) {
            int f4 = t + i * 256;
            int r = f4 >> 3, k4 = f4 & 7;
            int row = bm + r;
            int col = kc * 32 + k4 * 4;
            float4 v = make_float4(0.f, 0.f, 0.f, 0.f);
            if (row < M) {
                float4 y = *(const float4*)&Yin[(size_t)row * 128 + col];
                float4 scv = *(const float4*)&sc[col];
                float4 shv = *(const float4*)&sh[col];
                v.x = fmaxf(y.x * scv.x + shv.x, 0.f);
                v.y = fmaxf(y.y * scv.y + shv.y, 0.f);
                v.z = fmaxf(y.z * scv.z + shv.z, 0.f);
                v.w = fmaxf(y.w * scv.w + shv.w, 0.f);
            }
            As[k4 * 4 + 0][r] = v.x;
            As[k4 * 4 + 1][r] = v.y;
            As[k4 * 4 + 2][r] = v.z;
            As[k4 * 4 + 3][r] = v.w;
        }
        __syncthreads();
#pragma unroll
        for (int kk = 0; kk < 32; kk++) {
            float4 a0 = *(float4*)&As[kk][ty * 8];
            float4 a1 = *(float4*)&As[kk][ty * 8 + 4];
            float4 b0 = *(float4*)&Bs[kc * 32 + kk][tx * 4];
            float4 b1 = *(float4*)&Bs[kc * 32 + kk][64 + tx * 4];
            float av[8] = {a0.x, a0.y, a0.z, a0.w, a1.x, a1.y, a1.z, a1.w};
            float bv[8] = {b0.x, b0.y, b0.z, b0.w, b1.x, b1.y, b1.z, b1.w};
#pragma unroll
            for (int i = 0; i < 8; i++)
#pragma unroll
                for (int j = 0; j < 8; j++) acc[i][j] += av[i] * bv[j];
        }
    }
#pragma unroll
    for (int i = 0; i < 8; i++) {
        int row = bm + ty * 8 + i;
        if (row < M) {
            float di = dinv[row];
            float4 o0, o1;
            o0.x = acc[i][0] * di; o0.y = acc[i][1] * di;
            o0.z = acc[i][2] * di; o0.w = acc[i][3] * di;
            o1.x = acc[i][4] * di; o1.y = acc[i][5] * di;
            o1.z = acc[i][6] * di; o1.w = acc[i][7] * di;
            *(float4*)&HWs[(size_t)row * 128 + tx * 4] = o0;
            *(float4*)&HWs[(size_t)row * 128 + 64 + tx * 4] = o1;
        }
    }
}

// ---------------------------------------------------------------------------
// BN stats (for gcn output): 64 rows/block, unroll-4, f64 partials
// ---------------------------------------------------------------------------
#define BN2_ROWS 64
#define BN2_NB ((NN + BN2_ROWS - 1) / BN2_ROWS)   // 782

__global__ __launch_bounds__(128) void bn_stats(const float* __restrict__ Y,
                                                double* __restrict__ part, int M) {
    int c = threadIdx.x;
    int b = blockIdx.x;
    int r0 = b * BN2_ROWS;
    int r1 = min(M, r0 + BN2_ROWS);
    double s = 0.0, s2 = 0.0;
    int r = r0;
    for (; r + 4 <= r1; r += 4) {
        float v0 = Y[(size_t)r * 128 + c];
        float v1 = Y[(size_t)(r + 1) * 128 + c];
        float v2 = Y[(size_t)(r + 2) * 128 + c];
        float v3 = Y[(size_t)(r + 3) * 128 + c];
        s += (double)v0 + (double)v1 + (double)v2 + (double)v3;
        s2 += (double)v0 * v0 + (double)v1 * v1 + (double)v2 * v2 + (double)v3 * v3;
    }
    for (; r < r1; r++) {
        float v = Y[(size_t)r * 128 + c];
        s += (double)v;
        s2 += (double)v * v;
    }
    part[((size_t)b * 128 + c) * 2 + 0] = s;
    part[((size_t)b * 128 + c) * 2 + 1] = s2;
}

// ---------------------------------------------------------------------------
// BN finalize: parallel — one block per channel, 256 threads, LDS f64 tree.
// ---------------------------------------------------------------------------
__global__ __launch_bounds__(256) void bn_finalize(const double* __restrict__ part, int nb,
                                                   const float* __restrict__ g,
                                                   const float* __restrict__ beta,
                                                   float* __restrict__ scale,
                                                   float* __restrict__ shift, int M) {
    int c = blockIdx.x;
    int t = threadIdx.x;
    double s = 0.0, s2 = 0.0;
    for (int b = t; b < nb; b += 256) {
        s += part[((size_t)b * 128 + c) * 2 + 0];
        s2 += part[((size_t)b * 128 + c) * 2 + 1];
    }
    __shared__ double sd[256], sd2[256];
    sd[t] = s;
    sd2[t] = s2;
    __syncthreads();
#pragma unroll
    for (int o = 128; o > 0; o >>= 1) {
        if (t < o) {
            sd[t] += sd[t + o];
            sd2[t] += sd2[t + o];
        }
        __syncthreads();
    }
    if (t == 0) {
        double S = sd[0], S2 = sd2[0];
        double mu = S / (double)M;
        double var = S2 / (double)M - mu * mu;
        double inv = 1.0 / sqrt(var + (double)EPSF);
        scale[c] = (float)((double)g[c] * inv);
        shift[c] = (float)((double)beta[c] - mu * (double)g[c] * inv);
    }
}

// ---------------------------------------------------------------------------
// Graph: degree count, CSR build
// ---------------------------------------------------------------------------
__global__ __launch_bounds__(256) void count_deg(const int* __restrict__ col,
                                                 int* __restrict__ cnt, int E) {
    int e = blockIdx.x * 256 + threadIdx.x;
    if (e < E) atomicAdd(&cnt[col[e]], 1);
}

__global__ __launch_bounds__(256) void fill_csr(const int* __restrict__ row,
                                                const int* __restrict__ col,
                                                const int* __restrict__ off,
                                                int* __restrict__ cur,
                                                int* __restrict__ csr, int E) {
    int e = blockIdx.x * 256 + threadIdx.x;
    if (e < E) {
        int c = col[e];
        int p = atomicAdd(&cur[c], 1);
        csr[off[c] + p] = row[e];
    }
}

// ---------------------------------------------------------------------------
// Scan (3-phase exclusive scan; phase1 optionally emits dinv = rsqrt(cnt+1))
// ---------------------------------------------------------------------------
__device__ __forceinline__ int waveInclScan(int v, int lane) {
#pragma unroll
    for (int o = 1; o < 64; o <<= 1) {
        int u = __shfl_up(v, o, 64);
        if (lane >= o) v += u;
    }
    return v;
}

__global__ __launch_bounds__(1024) void scan_phase1(const int* __restrict__ in,
                                                    int* __restrict__ out,
                                                    int* __restrict__ bsum,
                                                    float* __restrict__ dinv, int n) {
    int t = threadIdx.x;
    int g = blockIdx.x * 1024 + t;
    int lane = t & 63, wid = t >> 6;
    int v = (g < n) ? in[g] : 0;
    if (dinv && g < n) dinv[g] = (float)(1.0 / sqrt((double)(v + 1)));
    int incl = waveInclScan(v, lane);
    __shared__ int ws[16];
    if (lane == 63) ws[wid] = incl;
    __syncthreads();
    if (t < 16) {
        int x = ws[t];
#pragma unroll
        for (int o = 1; o < 16; o <<= 1) {
            int u = __shfl_up(x, o, 64);
            if (t >= o) x += u;
        }
        ws[t] = x;
    }
    __syncthreads();
    int pre = (wid > 0) ? ws[wid - 1] : 0;
    if (g < n) out[g] = pre + incl - v;
    if (t == 1023) bsum[blockIdx.x] = ws[15];
}

__global__ __launch_bounds__(1024) void scan_phase2(int* __restrict__ bsum, int B,
                                                    int* __restrict__ out, int n) {
    int t = threadIdx.x;
    int lane = t & 63, wid = t >> 6;
    int v = (t < B) ? bsum[t] : 0;
    int incl = waveInclScan(v, lane);
    __shared__ int ws[16];
    if (lane == 63) ws[wid] = incl;
    __syncthreads();
    if (t < 16) {
        int x = ws[t];
#pragma unroll
        for (int o = 1; o < 16; o <<= 1) {
            int u = __shfl_up(x, o, 64);
            if (t >= o) x += u;
        }
        ws[t] = x;
    }
    __syncthreads();
    int pre = (wid > 0) ? ws[wid - 1] : 0;
    int glob_incl = pre + incl;
    if (t < B) bsum[t] = glob_incl - v;   // exclusive
    if (t == B - 1) out[n] = glob_incl;   // grand total
}

__global__ __launch_bounds__(1024) void scan_phase3(int* __restrict__ out,
                                                    const int* __restrict__ bsum, int n) {
    int g = blockIdx.x * 1024 + threadIdx.x;
    if (g < n) out[g] += bsum[blockIdx.x];
}

// ---------------------------------------------------------------------------
// GCN aggregation: one WAVE per node (4 nodes / 256-thr block), float2 per
// lane, unroll-8 gathers for MLP. HWs is pre-scaled by dinv[src].
// OUT[i] = dinv[i]*( sum_src HWs[src] + HWs[i] ) + gcn_b
// ---------------------------------------------------------------------------
__global__ __launch_bounds__(256) void gcn_agg(const float* __restrict__ HWs,
                                               const int* __restrict__ off,
                                               const int* __restrict__ csr,
                                               const float* __restrict__ dinv,
                                               const float* __restrict__ gcn_b,
                                               float* __restrict__ OUT, int M) {
    int lane = threadIdx.x & 63;
    int i = blockIdx.x * 4 + (threadIdx.x >> 6);
    if (i >= M) return;
    const float2* H2 = (const float2*)HWs;
    int o0 = off[i], o1 = off[i + 1];
    float2 hv = H2[(size_t)i * 64 + lane];   // self loop term
    double ax = (double)hv.x, ay = (double)hv.y;
    int e = o0;
    for (; e + 8 <= o1; e += 8) {
        int s0 = csr[e], s1 = csr[e + 1], s2 = csr[e + 2], s3 = csr[e + 3];
        int s4 = csr[e + 4], s5 = csr[e + 5], s6 = csr[e + 6], s7 = csr[e + 7];
        float2 v0 = H2[(size_t)s0 * 64 + lane];
        float2 v1 = H2[(size_t)s1 * 64 + lane];
        float2 v2 = H2[(size_t)s2 * 64 + lane];
        float2 v3 = H2[(size_t)s3 * 64 + lane];
        float2 v4 = H2[(size_t)s4 * 64 + lane];
        float2 v5 = H2[(size_t)s5 * 64 + lane];
        float2 v6 = H2[(size_t)s6 * 64 + lane];
        float2 v7 = H2[(size_t)s7 * 64 + lane];
        ax += ((double)v0.x + (double)v1.x) + ((double)v2.x + (double)v3.x) +
              ((double)v4.x + (double)v5.x) + ((double)v6.x + (double)v7.x);
        ay += ((double)v0.y + (double)v1.y) + ((double)v2.y + (double)v3.y) +
              ((double)v4.y + (double)v5.y) + ((double)v6.y + (double)v7.y);
    }
    for (; e < o1; e++) {
        float2 v = H2[(size_t)csr[e] * 64 + lane];
        ax += (double)v.x;
        ay += (double)v.y;
    }
    double di = (double)dinv[i];
    float2 ob = ((const float2*)gcn_b)[lane];
    float2 o;
    o.x = (float)(ax * di) + ob.x;
    o.y = (float)(ay * di) + ob.y;
    ((float2*)OUT)[(size_t)i * 64 + lane] = o;
}

// ---------------------------------------------------------------------------
// Score (BN2+ReLU on the fly) + orderable key + bucket histogram. Wave/row.
// KEY IS THE RAW PRE-TANH v: tanh is monotone so ranking is identical, and
// v's exponent spread avoids tanh-saturation bucket blowup (rank was O(bkt)).
// ---------------------------------------------------------------------------
__global__ __launch_bounds__(256) void score_key(const float* __restrict__ Y2,
                                                 const float* __restrict__ sc,
                                                 const float* __restrict__ sh,
                                                 const float* __restrict__ w,
                                                 float* __restrict__ score,
                                                 unsigned* __restrict__ key,
                                                 int* __restrict__ bcnt, int M) {
    int lane = threadIdx.x & 63;
    int wid = threadIdx.x >> 6;
    int gw = blockIdx.x * 4 + wid;
    int nw = gridDim.x * 4;

    float w0 = w[lane], w1 = w[lane + 64];
    float sc0 = sc[lane], sh0 = sh[lane];
    float sc1 = sc[lane + 64], sh1 = sh[lane + 64];

    float nv = w0 * w0 + w1 * w1;
#pragma unroll
    for (int o = 32; o >= 1; o >>= 1) nv += __shfl_xor(nv, o, 64);
    float nrm = sqrtf(nv);

    for (int r = gw; r < M; r += nw) {
        float a = Y2[(size_t)r * 128 + lane];
        float b = Y2[(size_t)r * 128 + lane + 64];
        a = fmaxf(a * sc0 + sh0, 0.f);
        b = fmaxf(b * sc1 + sh1, 0.f);
        float v = a * w0 + b * w1;
#pragma unroll
        for (int o = 32; o >= 1; o >>= 1) v += __shfl_xor(v, o, 64);
        if (lane == 0) {
            score[r] = tanhf(v / nrm);
            unsigned u = __float_as_uint(v);
            unsigned k = (u & 0x80000000u) ? ~u : (u | 0x80000000u);
            key[r] = k;
            atomicAdd(&bcnt[k >> 16], 1);
        }
    }
}

__global__ __launch_bounds__(256) void bucket_fill(const unsigned* __restrict__ key,
                                                   const int* __restrict__ boff,
                                                   int* __restrict__ bcur,
                                                   int* __restrict__ bmem, int M) {
    int i = blockIdx.x * 256 + threadIdx.x;
    if (i < M) {
        int b = key[i] >> 16;
        int p = atomicAdd(&bcur[b], 1);
        bmem[boff[b] + p] = i;
    }
}

__global__ __launch_bounds__(256) void rank_kernel(const unsigned* __restrict__ key,
                                                   const int* __restrict__ boff,
                                                   const int* __restrict__ bmem,
                                                   int* __restrict__ rank,
                                                   int* __restrict__ nidx, int M) {
    int i = blockIdx.x * 256 + threadIdx.x;
    if (i >= M) return;
    unsigned ki = key[i];
    int b = ki >> 16;
    int r = M - boff[b + 1];   // all keys in strictly-greater buckets
    int p0 = boff[b], p1 = boff[b + 1];
    for (int p = p0; p < p1; p++) {
        int j = bmem[p];
        unsigned kj = key[j];
        if (kj > ki || (kj == ki && j < i)) r++;
    }
    rank[i] = r;
    nidx[i] = (r < KTOP) ? r : -1;
}

// ---------------------------------------------------------------------------
// Output writers (d_out: [x_pool K*128 | ei_new 2E | batch_new K], all f32)
// write_pool: 4 nodes per 128-thr block, float4 per thread (32 thr/node)
// ---------------------------------------------------------------------------
__global__ __launch_bounds__(128) void write_pool(const float* __restrict__ Y2,
                                                  const float* __restrict__ sc,
                                                  const float* __restrict__ sh,
                                                  const float* __restrict__ score,
                                                  const int* __restrict__ rank,
                                                  float* __restrict__ out0,
                                                  float* __restrict__ out2, int M) {
    int sub = threadIdx.x >> 5;              // 0..3 node within block
    int c4 = threadIdx.x & 31;               // float4 index 0..31
    int i = blockIdx.x * 4 + sub;
    if (i >= M) return;
    int r = rank[i];
    if (r < KTOP) {
        float s = score[i];
        float4 y = *(const float4*)&Y2[(size_t)i * 128 + c4 * 4];
        float4 scv = *(const float4*)&sc[c4 * 4];
        float4 shv = *(const float4*)&sh[c4 * 4];
        float4 o;
        o.x = fmaxf(y.x * scv.x + shv.x, 0.f) * s;
        o.y = fmaxf(y.y * scv.y + shv.y, 0.f) * s;
        o.z = fmaxf(y.z * scv.z + shv.z, 0.f) * s;
        o.w = fmaxf(y.w * scv.w + shv.w, 0.f) * s;
        *(float4*)&out0[(size_t)r * 128 + c4 * 4] = o;
        if (c4 == 0) out2[r] = 0.0f;   // batch_new (batch is all zeros)
    }
}

__global__ __launch_bounds__(256) void write_edges(const int* __restrict__ row,
                                                   const int* __restrict__ col,
                                                   const int* __restrict__ nidx,
                                                   float* __restrict__ out1, int E) {
    int e = blockIdx.x * 256 + threadIdx.x;
    if (e < E) {
        int a = nidx[row[e]];
        int b = nidx[col[e]];
        bool keep = (a >= 0) && (b >= 0);
        out1[e] = keep ? (float)a : -1.0f;
        out1[E + e] = keep ? (float)b : -1.0f;
    }
}

// ---------------------------------------------------------------------------
extern "C" void kernel_launch(void* const* d_in, const int* in_sizes, int n_in,
                              void* d_out, int out_size, void* d_ws, size_t ws_size,
                              hipStream_t stream) {
    const float* x = (const float*)d_in[0];
    const int* ei = (const int*)d_in[1];
    const float* lin_w = (const float*)d_in[3];
    const float* lin_b = (const float*)d_in[4];
    const float* bn1_g = (const float*)d_in[5];
    const float* bn1_b = (const float*)d_in[6];
    const float* gcn_w = (const float*)d_in[7];
    const float* gcn_b = (const float*)d_in[8];
    const float* bn2_g = (const float*)d_in[9];
    const float* bn2_b = (const float*)d_in[10];
    const float* pool_w = (const float*)d_in[11];

    const int* e_row = ei;        // edge_index[0]
    const int* e_col = ei + EE;   // edge_index[1]

    char* ws = (char*)d_ws;
    size_t off_b = 0;
    auto alloc = [&](size_t bytes) -> void* {
        void* p = ws + off_b;
        off_b = (off_b + bytes + 255) & ~(size_t)255;
        return p;
    };
    float* y = (float*)alloc((size_t)NN * 128 * 4);     // gemm1 out, later gcn out (y2)
    float* hws = (float*)alloc((size_t)NN * 128 * 4);   // dinv-scaled h @ gcn_w
    int* cnt = (int*)alloc(NN * 4);
    int* cur = (int*)alloc(NN * 4);
    int* offs = (int*)alloc((NN + 1) * 4);
    float* dinv = (float*)alloc(NN * 4);
    int* csr = (int*)alloc((size_t)EE * 4);
    float* score = (float*)alloc(NN * 4);
    unsigned* key = (unsigned*)alloc(NN * 4);
    int* rank = (int*)alloc(NN * 4);
    int* nidx = (int*)alloc(NN * 4);
    int* bcnt = (int*)alloc(65536 * 4);
    int* boff = (int*)alloc((65536 + 1) * 4);
    int* bcur = (int*)alloc(65536 * 4);
    int* bmem = (int*)alloc(NN * 4);
    double* part = (double*)alloc((size_t)BN2_NB * 128 * 2 * 8);
    float* scale1 = (float*)alloc(128 * 4);
    float* shift1 = (float*)alloc(128 * 4);
    float* scale2 = (float*)alloc(128 * 4);
    float* shift2 = (float*)alloc(128 * 4);
    int* bsum = (int*)alloc(128 * 4);

    float* out0 = (float*)d_out;                       // x_pool [K,128]
    float* out1 = out0 + (size_t)KTOP * 128;           // ei_new [2,E]
    float* out2 = out1 + (size_t)2 * EE;               // batch_new [K]

    int gemm_grid = (NN + 127) / 128;                  // 391

    // ---- graph prep (independent of feature path) ----
    hipMemsetAsync(cnt, 0, NN * 4, stream);
    hipMemsetAsync(cur, 0, NN * 4, stream);
    hipMemsetAsync(bcnt, 0, 65536 * 4, stream);
    hipMemsetAsync(bcur, 0, 65536 * 4, stream);
    count_deg<<<(EE + 255) / 256, 256, 0, stream>>>(e_col, cnt, EE);
    {
        int B = (NN + 1023) / 1024;
        scan_phase1<<<B, 1024, 0, stream>>>(cnt, offs, bsum, dinv, NN);
        scan_phase2<<<1, 1024, 0, stream>>>(bsum, B, offs, NN);
        scan_phase3<<<B, 1024, 0, stream>>>(offs, bsum, NN);
    }
    fill_csr<<<(EE + 255) / 256, 256, 0, stream>>>(e_row, e_col, offs, cur, csr, EE);

    // ---- MLP: Linear (+ fused BN1 stats) ----
    gemm_bn_stats<<<gemm_grid, 256, 0, stream>>>(x, lin_w, lin_b, y, part, NN);
    bn_finalize<<<128, 256, 0, stream>>>(part, gemm_grid, bn1_g, bn1_b, scale1, shift1, NN);

    // ---- GCN: (BN1+ReLU fused) @ gcn_w, pre-scaled by dinv ----
    gemm_bn_apply<<<gemm_grid, 256, 0, stream>>>(y, gcn_w, scale1, shift1, dinv, hws, NN);
    gcn_agg<<<(NN + 3) / 4, 256, 0, stream>>>(hws, offs, csr, dinv, gcn_b, y, NN);

    // ---- BN2 stats ----
    bn_stats<<<BN2_NB, 128, 0, stream>>>(y, part, NN);
    bn_finalize<<<128, 256, 0, stream>>>(part, BN2_NB, bn2_g, bn2_b, scale2, shift2, NN);

    // ---- TopK pooling (BN2+ReLU fused into consumers) ----
    score_key<<<512, 256, 0, stream>>>(y, scale2, shift2, pool_w, score, key, bcnt, NN);
    {
        int B = 65536 / 1024;
        scan_phase1<<<B, 1024, 0, stream>>>(bcnt, boff, bsum, nullptr, 65536);
        scan_phase2<<<1, 1024, 0, stream>>>(bsum, B, boff, 65536);
        scan_phase3<<<B, 1024, 0, stream>>>(boff, bsum, 65536);
    }
    bucket_fill<<<(NN + 255) / 256, 256, 0, stream>>>(key, boff, bcur, bmem, NN);
    rank_kernel<<<(NN + 255) / 256, 256, 0, stream>>>(key, boff, bmem, rank, nidx, NN);

    // ---- outputs ----
    write_pool<<<(NN + 3) / 4, 128, 0, stream>>>(y, scale2, shift2, score, rank, out0, out2, NN);
    write_edges<<<(EE + 255) / 256, 256, 0, stream>>>(e_row, e_col, nidx, out1, EE);
}